// Round 20
// baseline (2542.453 us; speedup 1.0000x reference)
//
#include <hip/hip_runtime.h>
#include <math.h>

#define N_NODES 100000
#define N_GRAPHS 100
#define N_EDGES 1000000
#define H 256
#define L_POS 512
#define NBUCK4 (4 * N_NODES)
#define NBLKT ((N_NODES + 255) / 256)
#define OSLICE 8

typedef short bf16x8 __attribute__((ext_vector_type(8)));
typedef float f32x4  __attribute__((ext_vector_type(4)));

__device__ inline short f2bf(float f) {
    union { float f; unsigned u; } v; v.f = f;
    unsigned r = (v.u + 0x7FFF + ((v.u >> 16) & 1)) >> 16;
    return (short)r;
}
__device__ inline float bf2f(unsigned short u) {
    union { unsigned u; float f; } v; v.u = ((unsigned)u) << 16;
    return v.f;
}

// fast transcendentals (hw v_exp_f32 path)
__device__ inline float fsigm(float x) { return 1.0f / (1.0f + __expf(-x)); }
__device__ inline float ftanh(float x) {
    float t = __expf(-2.0f * fabsf(x));
    float y = 1.0f - 2.0f * t / (1.0f + t);
    return copysignf(y, x);
}

// async global->LDS, 16B per lane; lds dest = wave-uniform base + lane*16
__device__ inline void async16(short* l, const short* g) {
    __builtin_amdgcn_global_load_lds(
        (const __attribute__((address_space(1))) void*)g,
        (__attribute__((address_space(3))) void*)l, 16, 0, 0);
}

// ---------------- zero ints ----------------
__global__ void zero_int(int4* __restrict__ p, int n4)
{
    int i = blockIdx.x * 256 + threadIdx.x;
    if (i < n4) p[i] = make_int4(0, 0, 0, 0);
}

// ---------------- PE table ----------------
__global__ void pe_kernel(float* __restrict__ pe)
{
    int p = blockIdx.x;
    int j = threadIdx.x;
    float v = 0.0f;
    if (p > 0) {
        float pos = (float)(p - 1);
        float denom = powf(10000.0f, 2.0f * (float)j / (float)H);
        float ang = pos / denom;
        v = (j & 1) ? cosf(ang) : sinf(ang);
    }
    pe[p * H + j] = v;
}

// ---------------- init h (bf16) ----------------
__global__ void init_h_kernel(const int* __restrict__ nodes,
                              const float* __restrict__ embed,
                              const float* __restrict__ pe,
                              short* __restrict__ h)
{
    int n = blockIdx.x;
    int j = threadIdx.x;
    int tok = nodes[n];
    int p = nodes[N_NODES + n];
    if (p > L_POS) p = L_POS;
    h[(size_t)n * H + j] = f2bf(embed[(size_t)tok * H + j] + pe[p * H + j]);
}

// ---------------- weight prep ----------------
__global__ void cvt_wstack(const float* __restrict__ w, short* __restrict__ wt)
{
    int idx = blockIdx.x * 256 + threadIdx.x;
    if (idx >= 2 * 256 * 1024) return;
    int l = idx / (256 * 1024);
    int rem = idx % (256 * 1024);
    int n = rem >> 10, k = rem & 1023;
    int t = k >> 8, kk = k & 255;
    wt[idx] = f2bf(w[(((size_t)(l * 4 + t)) * 256 + kk) * 256 + n]);
}
// permuted column for GRU-fused epilogue: gate g, feature f -> p
__host__ __device__ inline int permcol(int g, int f)
{
    return ((f >> 4) << 6) + (g << 4) + (f & 15);
}
__global__ void cvt_comb(const float* __restrict__ W, const float* __restrict__ U,
                         short* __restrict__ B)
{
    int idx = blockIdx.x * 256 + threadIdx.x;
    if (idx >= 2 * 1024 * 512) return;
    int l = idx / (1024 * 512);
    int rem = idx % (1024 * 512);
    int n = rem >> 9, k = rem & 511;
    float v = 0.0f;
    if (n < 512) {
        v = (k < 256) ? W[((size_t)l * 256 + k) * 768 + n]
                      : U[((size_t)l * 256 + (k - 256)) * 768 + n];
    } else if (n < 768) {
        if (k < 256) v = W[((size_t)l * 256 + k) * 768 + n];
    } else {
        if (k >= 256) v = U[((size_t)l * 256 + (k - 256)) * 768 + (n - 256)];
    }
    int g = n >> 8, f = n & 255;
    B[((size_t)l * 1024 + permcol(g, f)) * 512 + k] = f2bf(v);
}
__global__ void cvt_bias(const float* __restrict__ bi, const float* __restrict__ br,
                         float* __restrict__ biasC)
{
    int idx = blockIdx.x * 256 + threadIdx.x;
    if (idx >= 2048) return;
    int l = idx >> 10, n = idx & 1023;
    float v;
    if (n < 512)      v = bi[l * 768 + n] + br[l * 768 + n];
    else if (n < 768) v = bi[l * 768 + n];
    else              v = br[l * 768 + (n - 256)];
    int g = n >> 8, f = n & 255;
    biasC[(size_t)l * 1024 + permcol(g, f)] = v;
}

// ---------------- CSR build ----------------
__global__ void histo_kernel(const int* __restrict__ edges, int* __restrict__ counts4)
{
    int e = blockIdx.x * 256 + threadIdx.x;
    if (e >= N_EDGES) return;
    int t = edges[e * 3];
    int tg = edges[e * 3 + 2];
    atomicAdd(&counts4[t * N_NODES + tg], 1);
}
__device__ inline int cnt_tgt(const int* counts4, int i)
{
    return counts4[i] + counts4[N_NODES + i] + counts4[2 * N_NODES + i] + counts4[3 * N_NODES + i];
}
__global__ void scan1(const int* __restrict__ counts4, int* __restrict__ partial)
{
    __shared__ int s[256];
    int i = blockIdx.x * 256 + threadIdx.x;
    s[threadIdx.x] = (i < N_NODES) ? cnt_tgt(counts4, i) : 0;
    __syncthreads();
    for (int off = 128; off > 0; off >>= 1) {
        if (threadIdx.x < off) s[threadIdx.x] += s[threadIdx.x + off];
        __syncthreads();
    }
    if (threadIdx.x == 0) partial[blockIdx.x] = s[0];
}
__global__ void scan2(int* __restrict__ partial, int* __restrict__ offs)
{
    if (threadIdx.x == 0 && blockIdx.x == 0) {
        int run = 0;
        for (int i = 0; i < NBLKT; i++) { int v = partial[i]; partial[i] = run; run += v; }
        offs[N_NODES] = run;
    }
}
__global__ void scan3(const int* __restrict__ counts4, const int* __restrict__ partial,
                      int* __restrict__ offs)
{
    __shared__ int s[256];
    int i = blockIdx.x * 256 + threadIdx.x;
    int v = (i < N_NODES) ? cnt_tgt(counts4, i) : 0;
    s[threadIdx.x] = v;
    __syncthreads();
    for (int off = 1; off < 256; off <<= 1) {
        int add = (threadIdx.x >= off) ? s[threadIdx.x - off] : 0;
        __syncthreads();
        s[threadIdx.x] += add;
        __syncthreads();
    }
    if (i < N_NODES) offs[i] = partial[blockIdx.x] + s[threadIdx.x] - v;
}
__global__ void fill_kernel(const int* __restrict__ edges, const int* __restrict__ offs,
                            int* __restrict__ cursors, int* __restrict__ srcs)
{
    int e = blockIdx.x * 256 + threadIdx.x;
    if (e >= N_EDGES) return;
    int t = edges[e * 3];
    int s = edges[e * 3 + 1];
    int tg = edges[e * 3 + 2];
    int p = atomicAdd(&cursors[tg], 1);
    srcs[offs[tg] + p] = s | (t << 17);
}

// ---- gather: deep-MLP batching (8 row-loads in flight per wave) ----
__global__ __launch_bounds__(256) void gather_kernel(
    const int* __restrict__ offs, const int* __restrict__ srcs,
    const short* __restrict__ h, short* __restrict__ gath4, int c0, int nr)
{
    int w = (blockIdx.x * 256 + threadIdx.x) >> 6;
    int lane = threadIdx.x & 63;
    if (w >= nr) return;
    int tgt = c0 + w;
    int col = lane * 4;
    int e0 = offs[tgt], e1 = offs[tgt + 1];
    float4 a0 = make_float4(0.f,0.f,0.f,0.f), a1 = a0, a2 = a0, a3 = a0;

    #define ACCUM(V, PK) do {                                                  \
        float4 vv = make_float4(bf2f((unsigned short)((PK).x & 0xFFFF)),       \
                                bf2f((unsigned short)((PK).x >> 16)),          \
                                bf2f((unsigned short)((PK).y & 0xFFFF)),       \
                                bf2f((unsigned short)((PK).y >> 16)));         \
        int tt = (V) >> 17;                                                    \
        switch (tt) {                                                          \
        case 0: a0.x += vv.x; a0.y += vv.y; a0.z += vv.z; a0.w += vv.w; break; \
        case 1: a1.x += vv.x; a1.y += vv.y; a1.z += vv.z; a1.w += vv.w; break; \
        case 2: a2.x += vv.x; a2.y += vv.y; a2.z += vv.z; a2.w += vv.w; break; \
        default: a3.x += vv.x; a3.y += vv.y; a3.z += vv.z; a3.w += vv.w; }     \
    } while (0)

    int e = e0;
    for (; e + 8 <= e1; e += 8) {
        int v[8];
        #pragma unroll
        for (int i = 0; i < 8; i++)
            v[i] = __builtin_amdgcn_readfirstlane(srcs[e + i]);
        uint2 p[8];
        #pragma unroll
        for (int i = 0; i < 8; i++)
            p[i] = *(const uint2*)(h + (size_t)(v[i] & 0x1FFFF) * H + col);
        #pragma unroll
        for (int i = 0; i < 8; i++)
            ACCUM(v[i], p[i]);
    }
    if (e + 4 <= e1) {
        int v[4];
        #pragma unroll
        for (int i = 0; i < 4; i++)
            v[i] = __builtin_amdgcn_readfirstlane(srcs[e + i]);
        uint2 p[4];
        #pragma unroll
        for (int i = 0; i < 4; i++)
            p[i] = *(const uint2*)(h + (size_t)(v[i] & 0x1FFFF) * H + col);
        #pragma unroll
        for (int i = 0; i < 4; i++)
            ACCUM(v[i], p[i]);
        e += 4;
    }
    for (; e < e1; e++) {
        int v0 = __builtin_amdgcn_readfirstlane(srcs[e]);
        uint2 p0 = *(const uint2*)(h + (size_t)(v0 & 0x1FFFF) * H + col);
        ACCUM(v0, p0);
    }
    #undef ACCUM

    short* dst = gath4 + (size_t)w * 1024 + col;
    #define PACK(A) make_uint2( \
        ((unsigned)(unsigned short)f2bf((A).x)) | (((unsigned)(unsigned short)f2bf((A).y)) << 16), \
        ((unsigned)(unsigned short)f2bf((A).z)) | (((unsigned)(unsigned short)f2bf((A).w)) << 16))
    *(uint2*)(dst)       = PACK(a0);
    *(uint2*)(dst + 256) = PACK(a1);
    *(uint2*)(dst + 512) = PACK(a2);
    *(uint2*)(dst + 768) = PACK(a3);
    #undef PACK
}

// ---- mm1: bf16 MFMA matmul, async double-buffered LDS, ONE barrier per tile ----
__global__ __launch_bounds__(256) void mm_bf16(
    const short* __restrict__ A0, int s0, const short* __restrict__ A1, int s1, int K0,
    const short* __restrict__ BT, int Ktot,
    const float* __restrict__ bias,
    const int* __restrict__ cnt, int c0,
    short* __restrict__ C, int ldc, int nrows)
{
    __shared__ short As[2][128 * 32];
    __shared__ short Bs[2][128 * 32];
    const int tid = threadIdx.x;
    const int bm = blockIdx.x * 128;
    const int bn = blockIdx.y * 128;
    const int lane = tid & 63;
    const int wave = tid >> 6;
    const int wm = (wave >> 1) * 64;
    const int wn = (wave & 1) * 64;
    const int q = lane >> 4;
    const int r16 = lane & 15;

    f32x4 acc[4][4];
    #pragma unroll
    for (int i = 0; i < 4; i++)
        #pragma unroll
        for (int j = 0; j < 4; j++)
            acc[i][j] = (f32x4){0.f, 0.f, 0.f, 0.f};

    const int seg0 = wave * 2;
    const int rloc0 = seg0 * 16 + (lane >> 2);
    const int rloc1 = rloc0 + 16;
    const int un = (lane & 3) * 8;
    int ga0 = bm + rloc0; if (ga0 >= nrows) ga0 = nrows - 1;
    int ga1 = bm + rloc1; if (ga1 >= nrows) ga1 = nrows - 1;

    const short* b0p = BT + (size_t)(bn + rloc0) * Ktot + un;
    const short* b1p = BT + (size_t)(bn + rloc1) * Ktot + un;
    const short* a0p = A0 + (size_t)ga0 * s0 + un;
    const short* a1p = A0 + (size_t)ga1 * s0 + un;
    const int nT = Ktot >> 5;

    async16(&As[0][seg0 * 512], a0p);
    async16(&As[0][(seg0 + 1) * 512], a1p);
    async16(&Bs[0][seg0 * 512], b0p);
    async16(&Bs[0][(seg0 + 1) * 512], b1p);
    a0p += 32; a1p += 32; b0p += 32; b1p += 32;

    int buf = 0;
    for (int i = 0; i < nT; i++) {
        __syncthreads();
        if (i + 1 < nT) {
            int nb = buf ^ 1;
            async16(&As[nb][seg0 * 512], a0p);
            async16(&As[nb][(seg0 + 1) * 512], a1p);
            async16(&Bs[nb][seg0 * 512], b0p);
            async16(&Bs[nb][(seg0 + 1) * 512], b1p);
            a0p += 32; a1p += 32; b0p += 32; b1p += 32;
        }
        bf16x8 af[4], bfr[4];
        #pragma unroll
        for (int mt = 0; mt < 4; mt++)
            af[mt] = *(const bf16x8*)&As[buf][(wm + mt * 16 + r16) * 32 + q * 8];
        #pragma unroll
        for (int nt = 0; nt < 4; nt++)
            bfr[nt] = *(const bf16x8*)&Bs[buf][(wn + nt * 16 + r16) * 32 + q * 8];
        #pragma unroll
        for (int mt = 0; mt < 4; mt++)
            #pragma unroll
            for (int nt = 0; nt < 4; nt++)
                acc[mt][nt] = __builtin_amdgcn_mfma_f32_16x16x32_bf16(af[mt], bfr[nt], acc[mt][nt], 0, 0, 0);
        buf ^= 1;
    }

    #pragma unroll
    for (int mt = 0; mt < 4; mt++) {
        #pragma unroll
        for (int reg = 0; reg < 4; reg++) {
            int row = bm + wm + mt * 16 + q * 4 + reg;
            if (row >= nrows) continue;
            #pragma unroll
            for (int nt = 0; nt < 4; nt++) {
                int col = bn + wn + nt * 16 + r16;
                float v = acc[mt][nt][reg];
                if (cnt) {
                    #pragma unroll
                    for (int t = 0; t < 4; t++)
                        v += (float)cnt[t * N_NODES + c0 + row] * bias[t * 256 + col];
                } else {
                    v += bias[col];
                }
                C[(size_t)row * ldc + col] = f2bf(v);
            }
        }
    }
}

// ---- mm2 fused: S-matmul (permuted cols, async dbuf, one barrier/tile) + GRU ----
__global__ __launch_bounds__(256) void mm_gru(
    const short* __restrict__ A0, const short* __restrict__ A1,
    const short* __restrict__ BT,
    const float* __restrict__ bias,
    const short* __restrict__ hOld, short* __restrict__ hNew,
    int c0, int nrows)
{
    __shared__ short As[2][128 * 32];
    __shared__ short Bs[2][128 * 32];
    const int tid = threadIdx.x;
    const int bm = blockIdx.x * 128;
    const int bn = blockIdx.y * 128;
    const int lane = tid & 63;
    const int wave = tid >> 6;
    const int wm = (wave >> 1) * 64;
    const int wn = (wave & 1) * 64;
    const int q = lane >> 4;
    const int r16 = lane & 15;
    const int Ktot = 512;

    f32x4 acc[4][4];
    #pragma unroll
    for (int i = 0; i < 4; i++)
        #pragma unroll
        for (int j = 0; j < 4; j++)
            acc[i][j] = (f32x4){0.f, 0.f, 0.f, 0.f};

    const int seg0 = wave * 2;
    const int rloc0 = seg0 * 16 + (lane >> 2);
    const int rloc1 = rloc0 + 16;
    const int un = (lane & 3) * 8;
    int ga0 = bm + rloc0; if (ga0 >= nrows) ga0 = nrows - 1;
    int ga1 = bm + rloc1; if (ga1 >= nrows) ga1 = nrows - 1;

    const short* b0p = BT + (size_t)(bn + rloc0) * Ktot + un;
    const short* b1p = BT + (size_t)(bn + rloc1) * Ktot + un;
    const short* a0p = A0 + (size_t)ga0 * 256 + un;
    const short* a1p = A0 + (size_t)ga1 * 256 + un;

    async16(&As[0][seg0 * 512], a0p);
    async16(&As[0][(seg0 + 1) * 512], a1p);
    async16(&Bs[0][seg0 * 512], b0p);
    async16(&Bs[0][(seg0 + 1) * 512], b1p);
    a0p += 32; a1p += 32; b0p += 32; b1p += 32;

    int buf = 0;
    for (int i = 0; i < 16; i++) {
        __syncthreads();
        if (i + 1 < 16) {
            int nb = buf ^ 1;
            async16(&As[nb][seg0 * 512], a0p);
            async16(&As[nb][(seg0 + 1) * 512], a1p);
            async16(&Bs[nb][seg0 * 512], b0p);
            async16(&Bs[nb][(seg0 + 1) * 512], b1p);
            if (i + 2 == 8) {
                a0p = A1 + (size_t)ga0 * 256 + un;
                a1p = A1 + (size_t)ga1 * 256 + un;
            } else {
                a0p += 32; a1p += 32;
            }
            b0p += 32; b1p += 32;
        }
        bf16x8 af[4], bfr[4];
        #pragma unroll
        for (int mt = 0; mt < 4; mt++)
            af[mt] = *(const bf16x8*)&As[buf][(wm + mt * 16 + r16) * 32 + q * 8];
        #pragma unroll
        for (int nt = 0; nt < 4; nt++)
            bfr[nt] = *(const bf16x8*)&Bs[buf][(wn + nt * 16 + r16) * 32 + q * 8];
        #pragma unroll
        for (int mt = 0; mt < 4; mt++)
            #pragma unroll
            for (int nt = 0; nt < 4; nt++)
                acc[mt][nt] = __builtin_amdgcn_mfma_f32_16x16x32_bf16(af[mt], bfr[nt], acc[mt][nt], 0, 0, 0);
        buf ^= 1;
    }

    // GRU epilogue (fast transcendentals)
    const int f = ((bn + wn) >> 2) + r16;
    const float bz = bias[bn + wn + 0 * 16 + r16];
    const float br_ = bias[bn + wn + 1 * 16 + r16];
    const float bx = bias[bn + wn + 2 * 16 + r16];
    const float bh = bias[bn + wn + 3 * 16 + r16];
    #pragma unroll
    for (int mt = 0; mt < 4; mt++) {
        #pragma unroll
        for (int reg = 0; reg < 4; reg++) {
            int row = bm + wm + mt * 16 + q * 4 + reg;
            if (row >= nrows) continue;
            float vz = acc[mt][0][reg] + bz;
            float vr = acc[mt][1][reg] + br_;
            float vx = acc[mt][2][reg] + bx;
            float vh = acc[mt][3][reg] + bh;
            size_t idx = (size_t)(c0 + row) * H + f;
            float hv = bf2f((unsigned short)hOld[idx]);
            float z = fsigm(vz);
            float r = fsigm(vr);
            float cand = ftanh(vx + r * vh);
            hNew[idx] = f2bf(z * hv + (1.0f - z) * cand);
        }
    }
}

// ---------------- gate logits ----------------
__global__ __launch_bounds__(256) void gate_kernel(const short* __restrict__ h,
                                                   const float* __restrict__ gW,
                                                   const float* __restrict__ gb,
                                                   float* __restrict__ g)
{
    int tid = blockIdx.x * 256 + threadIdx.x;
    int n = tid >> 6;
    if (n >= N_NODES) return;
    int lane = tid & 63;
    uint2 pk = *(const uint2*)(h + (size_t)n * H + lane * 4);
    float4 w = *(const float4*)(gW + lane * 4);
    float s = bf2f((unsigned short)(pk.x & 0xFFFF)) * w.x
            + bf2f((unsigned short)(pk.x >> 16))    * w.y
            + bf2f((unsigned short)(pk.y & 0xFFFF)) * w.z
            + bf2f((unsigned short)(pk.y >> 16))    * w.w;
    #pragma unroll
    for (int off = 32; off > 0; off >>= 1)
        s += __shfl_down(s, off);
    if (lane == 0) g[n] = s + gb[0];
}

// ---------------- readout phase A: per-graph max & sumexp ----------------
__global__ __launch_bounds__(256) void outA_kernel(const float* __restrict__ g,
                                                   const int* __restrict__ sizes,
                                                   float* __restrict__ gm,
                                                   float* __restrict__ gs)
{
    __shared__ float red[256];
    int gid = blockIdx.x;
    int tid = threadIdx.x;
    int start = 0, end = 0;
    {
        int c = 0;
        for (int i = 0; i < N_GRAPHS; i++) {
            int sz = sizes[i];
            if (i == gid) { start = c; end = c + sz; }
            c += sz;
        }
    }
    float m = -INFINITY;
    for (int n = start + tid; n < end; n += 256) m = fmaxf(m, g[n]);
    red[tid] = m; __syncthreads();
    for (int s = 128; s > 0; s >>= 1) {
        if (tid < s) red[tid] = fmaxf(red[tid], red[tid + s]);
        __syncthreads();
    }
    m = red[0]; __syncthreads();
    float s_ = 0.0f;
    for (int n = start + tid; n < end; n += 256) s_ += __expf(g[n] - m);
    red[tid] = s_; __syncthreads();
    for (int s = 128; s > 0; s >>= 1) {
        if (tid < s) red[tid] += red[tid + s];
        __syncthreads();
    }
    if (tid == 0) { gm[gid] = m; gs[gid] = red[0]; }
}

// ---------------- readout phase B: sliced e-weighted feature sums ----------------
__global__ __launch_bounds__(256) void outB_kernel(const short* __restrict__ h,
                                                   const float* __restrict__ g,
                                                   const int* __restrict__ sizes,
                                                   const float* __restrict__ gm,
                                                   float* __restrict__ accb)
{
    __shared__ float red4[4][256];
    int gid = blockIdx.x / OSLICE;
    int si = blockIdx.x % OSLICE;
    int tid = threadIdx.x;
    int wave = tid >> 6;
    int lane = tid & 63;
    int start = 0, end = 0;
    {
        int c = 0;
        for (int i = 0; i < N_GRAPHS; i++) {
            int sz = sizes[i];
            if (i == gid) { start = c; end = c + sz; }
            c += sz;
        }
    }
    float m = gm[gid];
    float a0 = 0.f, a1 = 0.f, a2 = 0.f, a3 = 0.f;
    for (int n = start + si * 4 + wave; n < end; n += OSLICE * 4) {
        float e = __expf(g[n] - m);
        uint2 pk = *(const uint2*)(h + (size_t)n * H + lane * 4);
        a0 += e * bf2f((unsigned short)(pk.x & 0xFFFF));
        a1 += e * bf2f((unsigned short)(pk.x >> 16));
        a2 += e * bf2f((unsigned short)(pk.y & 0xFFFF));
        a3 += e * bf2f((unsigned short)(pk.y >> 16));
    }
    red4[wave][lane * 4 + 0] = a0;
    red4[wave][lane * 4 + 1] = a1;
    red4[wave][lane * 4 + 2] = a2;
    red4[wave][lane * 4 + 3] = a3;
    __syncthreads();
    float acc = red4[0][tid] + red4[1][tid] + red4[2][tid] + red4[3][tid];
    unsafeAtomicAdd(&accb[(size_t)gid * 256 + tid], acc);
}

// ---------------- readout phase C: project to outputs ----------------
__global__ __launch_bounds__(256) void outC_kernel(const float* __restrict__ accb,
                                                   const float* __restrict__ gs,
                                                   const float* __restrict__ outW,
                                                   const float* __restrict__ outBs,
                                                   float* __restrict__ out)
{
    __shared__ float red[256];
    int gid = blockIdx.x;
    int tid = threadIdx.x;
    float ssum = gs[gid];
    float inv = 1.0f / (ssum + 1e-16f);
    float a = accb[(size_t)gid * 256 + tid];
    for (int c = 0; c < 2; c++) {
        red[tid] = a * outW[tid * 2 + c];
        __syncthreads();
        for (int s = 128; s > 0; s >>= 1) {
            if (tid < s) red[tid] += red[tid + s];
            __syncthreads();
        }
        if (tid == 0) out[gid * 2 + c] = red[0] * inv + outBs[c] * (ssum * inv);
        __syncthreads();
    }
}

static inline size_t alup(size_t x) { return (x + 255) & ~(size_t)255; }

extern "C" void kernel_launch(void* const* d_in, const int* in_sizes, int n_in,
                              void* d_out, int out_size, void* d_ws, size_t ws_size,
                              hipStream_t stream)
{
    const int*   nodes  = (const int*)d_in[0];
    const int*   gsizes = (const int*)d_in[1];
    const int*   edges  = (const int*)d_in[2];
    const float* embed  = (const float*)d_in[3];
    const float* type_w = (const float*)d_in[4];
    const float* type_b = (const float*)d_in[5];
    const float* gru_W  = (const float*)d_in[6];
    const float* gru_U  = (const float*)d_in[7];
    const float* gru_bi = (const float*)d_in[8];
    const float* gru_br = (const float*)d_in[9];
    const float* gate_W = (const float*)d_in[10];
    const float* gate_b = (const float*)d_in[11];
    const float* out_W  = (const float*)d_in[12];
    const float* out_b  = (const float*)d_in[13];
    float* out = (float*)d_out;

    const int CHMAX = 33334;
    const int c0s[3] = {0, 33334, 66667};
    const int nrs[3] = {33334, 33333, 33333};

    // ---- workspace layout (bytes), total ~199 MB ----
    const size_t SZ_HB   = alup((size_t)N_NODES * H * 2);
    const size_t SZ_SCR1 = alup((size_t)CHMAX * 1024 * 2);
    const size_t SZ_SCR2 = alup((size_t)CHMAX * 256 * 2);
    const size_t SZ_G    = alup((size_t)N_NODES * 4);
    const size_t SZ_PE   = alup((size_t)(L_POS + 1) * H * 4);
    const size_t SZ_WST  = alup((size_t)2 * 256 * 1024 * 2);
    const size_t SZ_BC   = alup((size_t)2 * 1024 * 512 * 2);
    const size_t SZ_BIAS = alup((size_t)2 * 1024 * 4);
    const size_t SZ_CNT4 = alup((size_t)NBUCK4 * 4);
    const size_t SZ_CUR  = alup((size_t)N_NODES * 4);
    const size_t SZ_ACC  = alup((size_t)N_GRAPHS * 256 * 4);
    const size_t SZ_OFF  = alup((size_t)(N_NODES + 1) * 4);
    const size_t SZ_SRC  = alup((size_t)N_EDGES * 4);
    const size_t SZ_PART = alup((size_t)NBLKT * 4);
    const size_t SZ_GMS  = alup((size_t)N_GRAPHS * 4);
    size_t need = 2 * SZ_HB + SZ_SCR1 + SZ_SCR2 + SZ_G + SZ_PE + SZ_WST + SZ_BC + SZ_BIAS +
                  SZ_CNT4 + SZ_CUR + SZ_ACC + SZ_OFF + SZ_SRC + SZ_PART + 2 * SZ_GMS;
    if (ws_size < need) return;

    char* base = (char*)d_ws;
    short* hA     = (short*)base;  base += SZ_HB;
    short* hB     = (short*)base;  base += SZ_HB;
    short* scr1   = (short*)base;  base += SZ_SCR1;
    short* scr2   = (short*)base;  base += SZ_SCR2;
    float* g      = (float*)base;  base += SZ_G;
    float* peTab  = (float*)base;  base += SZ_PE;
    short* Wstack = (short*)base;  base += SZ_WST;
    short* Bcomb  = (short*)base;  base += SZ_BC;
    float* biasC  = (float*)base;  base += SZ_BIAS;
    int*   counts4= (int*)base;    base += SZ_CNT4;
    int*   cursors= (int*)base;    base += SZ_CUR;
    float* accb   = (float*)base;  base += SZ_ACC;
    int*   offs   = (int*)base;    base += SZ_OFF;
    int*   srcs   = (int*)base;    base += SZ_SRC;
    int*   partial= (int*)base;    base += SZ_PART;
    float* gm     = (float*)base;  base += SZ_GMS;
    float* gs     = (float*)base;  base += SZ_GMS;

    // ---- prep ----
    pe_kernel<<<L_POS + 1, 256, 0, stream>>>(peTab);
    cvt_wstack<<<(2 * 256 * 1024) / 256, 256, 0, stream>>>(type_w, Wstack);
    cvt_comb<<<(2 * 1024 * 512) / 256, 256, 0, stream>>>(gru_W, gru_U, Bcomb);
    cvt_bias<<<8, 256, 0, stream>>>(gru_bi, gru_br, biasC);
    {   // zero counts4 + cursors + accb (contiguous)
        int n4 = (int)((SZ_CNT4 + SZ_CUR + SZ_ACC) / 16);
        zero_int<<<(n4 + 255) / 256, 256, 0, stream>>>((int4*)counts4, n4);
    }
    histo_kernel<<<(N_EDGES + 255) / 256, 256, 0, stream>>>(edges, counts4);
    scan1<<<NBLKT, 256, 0, stream>>>(counts4, partial);
    scan2<<<1, 64, 0, stream>>>(partial, offs);
    scan3<<<NBLKT, 256, 0, stream>>>(counts4, partial, offs);
    fill_kernel<<<(N_EDGES + 255) / 256, 256, 0, stream>>>(edges, offs, cursors, srcs);
    init_h_kernel<<<N_NODES, H, 0, stream>>>(nodes, embed, peTab, hA);

    short* cur = hA;
    short* nxt = hB;
    const int steps[2] = {3, 1};
    for (int l = 0; l < 2; l++) {
        const short* WS = Wstack + (size_t)l * 256 * 1024;
        const float* Tb = type_b + (size_t)l * 4 * 256;
        const short* BC = Bcomb + (size_t)l * 1024 * 512;
        const float* Cb = biasC + (size_t)l * 1024;
        for (int s = 0; s < steps[l]; s++) {
            for (int c = 0; c < 3; c++) {
                int c0 = c0s[c], nr = nrs[c];
                int gb = (nr + 127) / 128;
                gather_kernel<<<(nr * 64 + 255) / 256, 256, 0, stream>>>(offs, srcs, cur, scr1, c0, nr);
                dim3 g1(gb, 2);
                mm_bf16<<<g1, 256, 0, stream>>>(scr1, 1024, nullptr, 0, 1024,
                                                WS, 1024, Tb, counts4, c0,
                                                scr2, 256, nr);
                dim3 g2(gb, 8);
                mm_gru<<<g2, 256, 0, stream>>>(scr2, cur + (size_t)c0 * H,
                                               BC, Cb, cur, nxt, c0, nr);
            }
            short* t = cur; cur = nxt; nxt = t;
        }
    }

    gate_kernel<<<(N_NODES * 64) / 256, 256, 0, stream>>>(cur, gate_W, gate_b, g);
    outA_kernel<<<N_GRAPHS, 256, 0, stream>>>(g, gsizes, gm, gs);
    outB_kernel<<<N_GRAPHS * OSLICE, 256, 0, stream>>>(cur, g, gsizes, gm, accb);
    outC_kernel<<<N_GRAPHS, 256, 0, stream>>>(accb, gs, out_W, out_b, out);
}

// Round 21
// 2158.244 us; speedup vs baseline: 1.1780x; 1.1780x over previous
//
#include <hip/hip_runtime.h>
#include <math.h>

#define N_NODES 100000
#define N_GRAPHS 100
#define N_EDGES 1000000
#define H 256
#define L_POS 512
#define NBUCK4 (4 * N_NODES)
#define NBLKT ((N_NODES + 255) / 256)
#define OSLICE 8

typedef short bf16x8 __attribute__((ext_vector_type(8)));
typedef float f32x4  __attribute__((ext_vector_type(4)));

__device__ inline short f2bf(float f) {
    union { float f; unsigned u; } v; v.f = f;
    unsigned r = (v.u + 0x7FFF + ((v.u >> 16) & 1)) >> 16;
    return (short)r;
}
__device__ inline float bf2f(unsigned short u) {
    union { unsigned u; float f; } v; v.u = ((unsigned)u) << 16;
    return v.f;
}

// fast transcendentals (hw v_exp_f32 path)
__device__ inline float fsigm(float x) { return 1.0f / (1.0f + __expf(-x)); }
__device__ inline float ftanh(float x) {
    float t = __expf(-2.0f * fabsf(x));
    float y = 1.0f - 2.0f * t / (1.0f + t);
    return copysignf(y, x);
}

// async global->LDS, 16B per lane; lds dest = wave-uniform base + lane*16
__device__ inline void async16(short* l, const short* g) {
    __builtin_amdgcn_global_load_lds(
        (const __attribute__((address_space(1))) void*)g,
        (__attribute__((address_space(3))) void*)l, 16, 0, 0);
}

// ---------------- zero ints ----------------
__global__ void zero_int(int4* __restrict__ p, int n4)
{
    int i = blockIdx.x * 256 + threadIdx.x;
    if (i < n4) p[i] = make_int4(0, 0, 0, 0);
}

// ---------------- PE table ----------------
__global__ void pe_kernel(float* __restrict__ pe)
{
    int p = blockIdx.x;
    int j = threadIdx.x;
    float v = 0.0f;
    if (p > 0) {
        float pos = (float)(p - 1);
        float denom = powf(10000.0f, 2.0f * (float)j / (float)H);
        float ang = pos / denom;
        v = (j & 1) ? cosf(ang) : sinf(ang);
    }
    pe[p * H + j] = v;
}

// ---------------- init h (bf16) ----------------
__global__ void init_h_kernel(const int* __restrict__ nodes,
                              const float* __restrict__ embed,
                              const float* __restrict__ pe,
                              short* __restrict__ h)
{
    int n = blockIdx.x;
    int j = threadIdx.x;
    int tok = nodes[n];
    int p = nodes[N_NODES + n];
    if (p > L_POS) p = L_POS;
    h[(size_t)n * H + j] = f2bf(embed[(size_t)tok * H + j] + pe[p * H + j]);
}

// ---------------- weight prep ----------------
__global__ void cvt_wstack(const float* __restrict__ w, short* __restrict__ wt)
{
    int idx = blockIdx.x * 256 + threadIdx.x;
    if (idx >= 2 * 256 * 1024) return;
    int l = idx / (256 * 1024);
    int rem = idx % (256 * 1024);
    int n = rem >> 10, k = rem & 1023;
    int t = k >> 8, kk = k & 255;
    wt[idx] = f2bf(w[(((size_t)(l * 4 + t)) * 256 + kk) * 256 + n]);
}
// permuted column for GRU-fused epilogue: gate g, feature f -> p
__host__ __device__ inline int permcol(int g, int f)
{
    return ((f >> 4) << 6) + (g << 4) + (f & 15);
}
__global__ void cvt_comb(const float* __restrict__ W, const float* __restrict__ U,
                         short* __restrict__ B)
{
    int idx = blockIdx.x * 256 + threadIdx.x;
    if (idx >= 2 * 1024 * 512) return;
    int l = idx / (1024 * 512);
    int rem = idx % (1024 * 512);
    int n = rem >> 9, k = rem & 511;
    float v = 0.0f;
    if (n < 512) {
        v = (k < 256) ? W[((size_t)l * 256 + k) * 768 + n]
                      : U[((size_t)l * 256 + (k - 256)) * 768 + n];
    } else if (n < 768) {
        if (k < 256) v = W[((size_t)l * 256 + k) * 768 + n];
    } else {
        if (k >= 256) v = U[((size_t)l * 256 + (k - 256)) * 768 + (n - 256)];
    }
    int g = n >> 8, f = n & 255;
    B[((size_t)l * 1024 + permcol(g, f)) * 512 + k] = f2bf(v);
}
__global__ void cvt_bias(const float* __restrict__ bi, const float* __restrict__ br,
                         float* __restrict__ biasC)
{
    int idx = blockIdx.x * 256 + threadIdx.x;
    if (idx >= 2048) return;
    int l = idx >> 10, n = idx & 1023;
    float v;
    if (n < 512)      v = bi[l * 768 + n] + br[l * 768 + n];
    else if (n < 768) v = bi[l * 768 + n];
    else              v = br[l * 768 + (n - 256)];
    int g = n >> 8, f = n & 255;
    biasC[(size_t)l * 1024 + permcol(g, f)] = v;
}

// ---------------- CSR build ----------------
__global__ void histo_kernel(const int* __restrict__ edges, int* __restrict__ counts4)
{
    int e = blockIdx.x * 256 + threadIdx.x;
    if (e >= N_EDGES) return;
    int t = edges[e * 3];
    int tg = edges[e * 3 + 2];
    atomicAdd(&counts4[t * N_NODES + tg], 1);
}
__device__ inline int cnt_tgt(const int* counts4, int i)
{
    return counts4[i] + counts4[N_NODES + i] + counts4[2 * N_NODES + i] + counts4[3 * N_NODES + i];
}
__global__ void scan1(const int* __restrict__ counts4, int* __restrict__ partial)
{
    __shared__ int s[256];
    int i = blockIdx.x * 256 + threadIdx.x;
    s[threadIdx.x] = (i < N_NODES) ? cnt_tgt(counts4, i) : 0;
    __syncthreads();
    for (int off = 128; off > 0; off >>= 1) {
        if (threadIdx.x < off) s[threadIdx.x] += s[threadIdx.x + off];
        __syncthreads();
    }
    if (threadIdx.x == 0) partial[blockIdx.x] = s[0];
}
__global__ void scan2(int* __restrict__ partial, int* __restrict__ offs)
{
    if (threadIdx.x == 0 && blockIdx.x == 0) {
        int run = 0;
        for (int i = 0; i < NBLKT; i++) { int v = partial[i]; partial[i] = run; run += v; }
        offs[N_NODES] = run;
    }
}
__global__ void scan3(const int* __restrict__ counts4, const int* __restrict__ partial,
                      int* __restrict__ offs)
{
    __shared__ int s[256];
    int i = blockIdx.x * 256 + threadIdx.x;
    int v = (i < N_NODES) ? cnt_tgt(counts4, i) : 0;
    s[threadIdx.x] = v;
    __syncthreads();
    for (int off = 1; off < 256; off <<= 1) {
        int add = (threadIdx.x >= off) ? s[threadIdx.x - off] : 0;
        __syncthreads();
        s[threadIdx.x] += add;
        __syncthreads();
    }
    if (i < N_NODES) offs[i] = partial[blockIdx.x] + s[threadIdx.x] - v;
}
__global__ void fill_kernel(const int* __restrict__ edges, const int* __restrict__ offs,
                            int* __restrict__ cursors, int* __restrict__ srcs)
{
    int e = blockIdx.x * 256 + threadIdx.x;
    if (e >= N_EDGES) return;
    int t = edges[e * 3];
    int s = edges[e * 3 + 1];
    int tg = edges[e * 3 + 2];
    int p = atomicAdd(&cursors[tg], 1);
    srcs[offs[tg] + p] = s | (t << 17);
}

// ---- gather: deep-MLP batching (8 row-loads in flight per wave) ----
__global__ __launch_bounds__(256) void gather_kernel(
    const int* __restrict__ offs, const int* __restrict__ srcs,
    const short* __restrict__ h, short* __restrict__ gath4, int c0, int nr)
{
    int w = (blockIdx.x * 256 + threadIdx.x) >> 6;
    int lane = threadIdx.x & 63;
    if (w >= nr) return;
    int tgt = c0 + w;
    int col = lane * 4;
    int e0 = offs[tgt], e1 = offs[tgt + 1];
    float4 a0 = make_float4(0.f,0.f,0.f,0.f), a1 = a0, a2 = a0, a3 = a0;

    #define ACCUM(V, PK) do {                                                  \
        float4 vv = make_float4(bf2f((unsigned short)((PK).x & 0xFFFF)),       \
                                bf2f((unsigned short)((PK).x >> 16)),          \
                                bf2f((unsigned short)((PK).y & 0xFFFF)),       \
                                bf2f((unsigned short)((PK).y >> 16)));         \
        int tt = (V) >> 17;                                                    \
        switch (tt) {                                                          \
        case 0: a0.x += vv.x; a0.y += vv.y; a0.z += vv.z; a0.w += vv.w; break; \
        case 1: a1.x += vv.x; a1.y += vv.y; a1.z += vv.z; a1.w += vv.w; break; \
        case 2: a2.x += vv.x; a2.y += vv.y; a2.z += vv.z; a2.w += vv.w; break; \
        default: a3.x += vv.x; a3.y += vv.y; a3.z += vv.z; a3.w += vv.w; }     \
    } while (0)

    int e = e0;
    for (; e + 8 <= e1; e += 8) {
        int v[8];
        #pragma unroll
        for (int i = 0; i < 8; i++)
            v[i] = __builtin_amdgcn_readfirstlane(srcs[e + i]);
        uint2 p[8];
        #pragma unroll
        for (int i = 0; i < 8; i++)
            p[i] = *(const uint2*)(h + (size_t)(v[i] & 0x1FFFF) * H + col);
        #pragma unroll
        for (int i = 0; i < 8; i++)
            ACCUM(v[i], p[i]);
    }
    if (e + 4 <= e1) {
        int v[4];
        #pragma unroll
        for (int i = 0; i < 4; i++)
            v[i] = __builtin_amdgcn_readfirstlane(srcs[e + i]);
        uint2 p[4];
        #pragma unroll
        for (int i = 0; i < 4; i++)
            p[i] = *(const uint2*)(h + (size_t)(v[i] & 0x1FFFF) * H + col);
        #pragma unroll
        for (int i = 0; i < 4; i++)
            ACCUM(v[i], p[i]);
        e += 4;
    }
    for (; e < e1; e++) {
        int v0 = __builtin_amdgcn_readfirstlane(srcs[e]);
        uint2 p0 = *(const uint2*)(h + (size_t)(v0 & 0x1FFFF) * H + col);
        ACCUM(v0, p0);
    }
    #undef ACCUM

    short* dst = gath4 + (size_t)w * 1024 + col;
    #define PACK(A) make_uint2( \
        ((unsigned)(unsigned short)f2bf((A).x)) | (((unsigned)(unsigned short)f2bf((A).y)) << 16), \
        ((unsigned)(unsigned short)f2bf((A).z)) | (((unsigned)(unsigned short)f2bf((A).w)) << 16))
    *(uint2*)(dst)       = PACK(a0);
    *(uint2*)(dst + 256) = PACK(a1);
    *(uint2*)(dst + 512) = PACK(a2);
    *(uint2*)(dst + 768) = PACK(a3);
    #undef PACK
}

// ---- mm1: bf16 MFMA matmul, async double-buffered LDS, ONE barrier per tile ----
__global__ __launch_bounds__(256) void mm_bf16(
    const short* __restrict__ A0, int s0, const short* __restrict__ A1, int s1, int K0,
    const short* __restrict__ BT, int Ktot,
    const float* __restrict__ bias,
    const int* __restrict__ cnt, int c0,
    short* __restrict__ C, int ldc, int nrows)
{
    __shared__ short As[2][128 * 32];
    __shared__ short Bs[2][128 * 32];
    const int tid = threadIdx.x;
    const int bm = blockIdx.x * 128;
    const int bn = blockIdx.y * 128;
    const int lane = tid & 63;
    const int wave = tid >> 6;
    const int wm = (wave >> 1) * 64;
    const int wn = (wave & 1) * 64;
    const int q = lane >> 4;
    const int r16 = lane & 15;

    f32x4 acc[4][4];
    #pragma unroll
    for (int i = 0; i < 4; i++)
        #pragma unroll
        for (int j = 0; j < 4; j++)
            acc[i][j] = (f32x4){0.f, 0.f, 0.f, 0.f};

    const int seg0 = wave * 2;
    const int rloc0 = seg0 * 16 + (lane >> 2);
    const int rloc1 = rloc0 + 16;
    const int un = (lane & 3) * 8;
    int ga0 = bm + rloc0; if (ga0 >= nrows) ga0 = nrows - 1;
    int ga1 = bm + rloc1; if (ga1 >= nrows) ga1 = nrows - 1;

    const short* b0p = BT + (size_t)(bn + rloc0) * Ktot + un;
    const short* b1p = BT + (size_t)(bn + rloc1) * Ktot + un;
    const short* a0p = A0 + (size_t)ga0 * s0 + un;
    const short* a1p = A0 + (size_t)ga1 * s0 + un;
    const int nT = Ktot >> 5;

    async16(&As[0][seg0 * 512], a0p);
    async16(&As[0][(seg0 + 1) * 512], a1p);
    async16(&Bs[0][seg0 * 512], b0p);
    async16(&Bs[0][(seg0 + 1) * 512], b1p);
    a0p += 32; a1p += 32; b0p += 32; b1p += 32;

    int buf = 0;
    for (int i = 0; i < nT; i++) {
        __syncthreads();
        if (i + 1 < nT) {
            int nb = buf ^ 1;
            async16(&As[nb][seg0 * 512], a0p);
            async16(&As[nb][(seg0 + 1) * 512], a1p);
            async16(&Bs[nb][seg0 * 512], b0p);
            async16(&Bs[nb][(seg0 + 1) * 512], b1p);
            a0p += 32; a1p += 32; b0p += 32; b1p += 32;
        }
        bf16x8 af[4], bfr[4];
        #pragma unroll
        for (int mt = 0; mt < 4; mt++)
            af[mt] = *(const bf16x8*)&As[buf][(wm + mt * 16 + r16) * 32 + q * 8];
        #pragma unroll
        for (int nt = 0; nt < 4; nt++)
            bfr[nt] = *(const bf16x8*)&Bs[buf][(wn + nt * 16 + r16) * 32 + q * 8];
        #pragma unroll
        for (int mt = 0; mt < 4; mt++)
            #pragma unroll
            for (int nt = 0; nt < 4; nt++)
                acc[mt][nt] = __builtin_amdgcn_mfma_f32_16x16x32_bf16(af[mt], bfr[nt], acc[mt][nt], 0, 0, 0);
        buf ^= 1;
    }

    #pragma unroll
    for (int mt = 0; mt < 4; mt++) {
        #pragma unroll
        for (int reg = 0; reg < 4; reg++) {
            int row = bm + wm + mt * 16 + q * 4 + reg;
            if (row >= nrows) continue;
            #pragma unroll
            for (int nt = 0; nt < 4; nt++) {
                int col = bn + wn + nt * 16 + r16;
                float v = acc[mt][nt][reg];
                if (cnt) {
                    #pragma unroll
                    for (int t = 0; t < 4; t++)
                        v += (float)cnt[t * N_NODES + c0 + row] * bias[t * 256 + col];
                } else {
                    v += bias[col];
                }
                C[(size_t)row * ldc + col] = f2bf(v);
            }
        }
    }
}

// ---- mm2 fused: S-matmul (permuted cols, async dbuf, one barrier/tile) + GRU ----
__global__ __launch_bounds__(256) void mm_gru(
    const short* __restrict__ A0, const short* __restrict__ A1,
    const short* __restrict__ BT,
    const float* __restrict__ bias,
    const short* __restrict__ hOld, short* __restrict__ hNew,
    int c0, int nrows)
{
    __shared__ short As[2][128 * 32];
    __shared__ short Bs[2][128 * 32];
    const int tid = threadIdx.x;
    const int bm = blockIdx.x * 128;
    const int bn = blockIdx.y * 128;
    const int lane = tid & 63;
    const int wave = tid >> 6;
    const int wm = (wave >> 1) * 64;
    const int wn = (wave & 1) * 64;
    const int q = lane >> 4;
    const int r16 = lane & 15;
    const int Ktot = 512;

    f32x4 acc[4][4];
    #pragma unroll
    for (int i = 0; i < 4; i++)
        #pragma unroll
        for (int j = 0; j < 4; j++)
            acc[i][j] = (f32x4){0.f, 0.f, 0.f, 0.f};

    const int seg0 = wave * 2;
    const int rloc0 = seg0 * 16 + (lane >> 2);
    const int rloc1 = rloc0 + 16;
    const int un = (lane & 3) * 8;
    int ga0 = bm + rloc0; if (ga0 >= nrows) ga0 = nrows - 1;
    int ga1 = bm + rloc1; if (ga1 >= nrows) ga1 = nrows - 1;

    const short* b0p = BT + (size_t)(bn + rloc0) * Ktot + un;
    const short* b1p = BT + (size_t)(bn + rloc1) * Ktot + un;
    const short* a0p = A0 + (size_t)ga0 * 256 + un;
    const short* a1p = A0 + (size_t)ga1 * 256 + un;

    async16(&As[0][seg0 * 512], a0p);
    async16(&As[0][(seg0 + 1) * 512], a1p);
    async16(&Bs[0][seg0 * 512], b0p);
    async16(&Bs[0][(seg0 + 1) * 512], b1p);
    a0p += 32; a1p += 32; b0p += 32; b1p += 32;

    int buf = 0;
    for (int i = 0; i < 16; i++) {
        __syncthreads();
        if (i + 1 < 16) {
            int nb = buf ^ 1;
            async16(&As[nb][seg0 * 512], a0p);
            async16(&As[nb][(seg0 + 1) * 512], a1p);
            async16(&Bs[nb][seg0 * 512], b0p);
            async16(&Bs[nb][(seg0 + 1) * 512], b1p);
            if (i + 2 == 8) {
                a0p = A1 + (size_t)ga0 * 256 + un;
                a1p = A1 + (size_t)ga1 * 256 + un;
            } else {
                a0p += 32; a1p += 32;
            }
            b0p += 32; b1p += 32;
        }
        bf16x8 af[4], bfr[4];
        #pragma unroll
        for (int mt = 0; mt < 4; mt++)
            af[mt] = *(const bf16x8*)&As[buf][(wm + mt * 16 + r16) * 32 + q * 8];
        #pragma unroll
        for (int nt = 0; nt < 4; nt++)
            bfr[nt] = *(const bf16x8*)&Bs[buf][(wn + nt * 16 + r16) * 32 + q * 8];
        #pragma unroll
        for (int mt = 0; mt < 4; mt++)
            #pragma unroll
            for (int nt = 0; nt < 4; nt++)
                acc[mt][nt] = __builtin_amdgcn_mfma_f32_16x16x32_bf16(af[mt], bfr[nt], acc[mt][nt], 0, 0, 0);
        buf ^= 1;
    }

    // GRU epilogue (fast transcendentals)
    const int f = ((bn + wn) >> 2) + r16;
    const float bz = bias[bn + wn + 0 * 16 + r16];
    const float br_ = bias[bn + wn + 1 * 16 + r16];
    const float bx = bias[bn + wn + 2 * 16 + r16];
    const float bh = bias[bn + wn + 3 * 16 + r16];
    #pragma unroll
    for (int mt = 0; mt < 4; mt++) {
        #pragma unroll
        for (int reg = 0; reg < 4; reg++) {
            int row = bm + wm + mt * 16 + q * 4 + reg;
            if (row >= nrows) continue;
            float vz = acc[mt][0][reg] + bz;
            float vr = acc[mt][1][reg] + br_;
            float vx = acc[mt][2][reg] + bx;
            float vh = acc[mt][3][reg] + bh;
            size_t idx = (size_t)(c0 + row) * H + f;
            float hv = bf2f((unsigned short)hOld[idx]);
            float z = fsigm(vz);
            float r = fsigm(vr);
            float cand = ftanh(vx + r * vh);
            hNew[idx] = f2bf(z * hv + (1.0f - z) * cand);
        }
    }
}

// ---------------- gate logits ----------------
__global__ __launch_bounds__(256) void gate_kernel(const short* __restrict__ h,
                                                   const float* __restrict__ gW,
                                                   const float* __restrict__ gb,
                                                   float* __restrict__ g)
{
    int tid = blockIdx.x * 256 + threadIdx.x;
    int n = tid >> 6;
    if (n >= N_NODES) return;
    int lane = tid & 63;
    uint2 pk = *(const uint2*)(h + (size_t)n * H + lane * 4);
    float4 w = *(const float4*)(gW + lane * 4);
    float s = bf2f((unsigned short)(pk.x & 0xFFFF)) * w.x
            + bf2f((unsigned short)(pk.x >> 16))    * w.y
            + bf2f((unsigned short)(pk.y & 0xFFFF)) * w.z
            + bf2f((unsigned short)(pk.y >> 16))    * w.w;
    #pragma unroll
    for (int off = 32; off > 0; off >>= 1)
        s += __shfl_down(s, off);
    if (lane == 0) g[n] = s + gb[0];
}

// ---------------- readout phase A: per-graph max & sumexp ----------------
__global__ __launch_bounds__(256) void outA_kernel(const float* __restrict__ g,
                                                   const int* __restrict__ sizes,
                                                   float* __restrict__ gm,
                                                   float* __restrict__ gs)
{
    __shared__ float red[256];
    int gid = blockIdx.x;
    int tid = threadIdx.x;
    int start = 0, end = 0;
    {
        int c = 0;
        for (int i = 0; i < N_GRAPHS; i++) {
            int sz = sizes[i];
            if (i == gid) { start = c; end = c + sz; }
            c += sz;
        }
    }
    float m = -INFINITY;
    for (int n = start + tid; n < end; n += 256) m = fmaxf(m, g[n]);
    red[tid] = m; __syncthreads();
    for (int s = 128; s > 0; s >>= 1) {
        if (tid < s) red[tid] = fmaxf(red[tid], red[tid + s]);
        __syncthreads();
    }
    m = red[0]; __syncthreads();
    float s_ = 0.0f;
    for (int n = start + tid; n < end; n += 256) s_ += __expf(g[n] - m);
    red[tid] = s_; __syncthreads();
    for (int s = 128; s > 0; s >>= 1) {
        if (tid < s) red[tid] += red[tid + s];
        __syncthreads();
    }
    if (tid == 0) { gm[gid] = m; gs[gid] = red[0]; }
}

// ---------------- readout phase B: sliced e-weighted feature sums ----------------
__global__ __launch_bounds__(256) void outB_kernel(const short* __restrict__ h,
                                                   const float* __restrict__ g,
                                                   const int* __restrict__ sizes,
                                                   const float* __restrict__ gm,
                                                   float* __restrict__ accb)
{
    __shared__ float red4[4][256];
    int gid = blockIdx.x / OSLICE;
    int si = blockIdx.x % OSLICE;
    int tid = threadIdx.x;
    int wave = tid >> 6;
    int lane = tid & 63;
    int start = 0, end = 0;
    {
        int c = 0;
        for (int i = 0; i < N_GRAPHS; i++) {
            int sz = sizes[i];
            if (i == gid) { start = c; end = c + sz; }
            c += sz;
        }
    }
    float m = gm[gid];
    float a0 = 0.f, a1 = 0.f, a2 = 0.f, a3 = 0.f;
    for (int n = start + si * 4 + wave; n < end; n += OSLICE * 4) {
        float e = __expf(g[n] - m);
        uint2 pk = *(const uint2*)(h + (size_t)n * H + lane * 4);
        a0 += e * bf2f((unsigned short)(pk.x & 0xFFFF));
        a1 += e * bf2f((unsigned short)(pk.x >> 16));
        a2 += e * bf2f((unsigned short)(pk.y & 0xFFFF));
        a3 += e * bf2f((unsigned short)(pk.y >> 16));
    }
    red4[wave][lane * 4 + 0] = a0;
    red4[wave][lane * 4 + 1] = a1;
    red4[wave][lane * 4 + 2] = a2;
    red4[wave][lane * 4 + 3] = a3;
    __syncthreads();
    float acc = red4[0][tid] + red4[1][tid] + red4[2][tid] + red4[3][tid];
    unsafeAtomicAdd(&accb[(size_t)gid * 256 + tid], acc);
}

// ---------------- readout phase C: project to outputs ----------------
__global__ __launch_bounds__(256) void outC_kernel(const float* __restrict__ accb,
                                                   const float* __restrict__ gs,
                                                   const float* __restrict__ outW,
                                                   const float* __restrict__ outBs,
                                                   float* __restrict__ out)
{
    __shared__ float red[256];
    int gid = blockIdx.x;
    int tid = threadIdx.x;
    float ssum = gs[gid];
    float inv = 1.0f / (ssum + 1e-16f);
    float a = accb[(size_t)gid * 256 + tid];
    for (int c = 0; c < 2; c++) {
        red[tid] = a * outW[tid * 2 + c];
        __syncthreads();
        for (int s = 128; s > 0; s >>= 1) {
            if (tid < s) red[tid] += red[tid + s];
            __syncthreads();
        }
        if (tid == 0) out[gid * 2 + c] = red[0] * inv + outBs[c] * (ssum * inv);
        __syncthreads();
    }
}

static inline size_t alup(size_t x) { return (x + 255) & ~(size_t)255; }

extern "C" void kernel_launch(void* const* d_in, const int* in_sizes, int n_in,
                              void* d_out, int out_size, void* d_ws, size_t ws_size,
                              hipStream_t stream)
{
    const int*   nodes  = (const int*)d_in[0];
    const int*   gsizes = (const int*)d_in[1];
    const int*   edges  = (const int*)d_in[2];
    const float* embed  = (const float*)d_in[3];
    const float* type_w = (const float*)d_in[4];
    const float* type_b = (const float*)d_in[5];
    const float* gru_W  = (const float*)d_in[6];
    const float* gru_U  = (const float*)d_in[7];
    const float* gru_bi = (const float*)d_in[8];
    const float* gru_br = (const float*)d_in[9];
    const float* gate_W = (const float*)d_in[10];
    const float* gate_b = (const float*)d_in[11];
    const float* out_W  = (const float*)d_in[12];
    const float* out_b  = (const float*)d_in[13];
    float* out = (float*)d_out;

    const int CHMAX = 33334;
    const int c0s[3] = {0, 33334, 66667};
    const int nrs[3] = {33334, 33333, 33333};

    // ---- workspace layout (bytes), total ~199 MB ----
    const size_t SZ_HB   = alup((size_t)N_NODES * H * 2);
    const size_t SZ_SCR1 = alup((size_t)CHMAX * 1024 * 2);
    const size_t SZ_SCR2 = alup((size_t)CHMAX * 256 * 2);
    const size_t SZ_G    = alup((size_t)N_NODES * 4);
    const size_t SZ_PE   = alup((size_t)(L_POS + 1) * H * 4);
    const size_t SZ_WST  = alup((size_t)2 * 256 * 1024 * 2);
    const size_t SZ_BC   = alup((size_t)2 * 1024 * 512 * 2);
    const size_t SZ_BIAS = alup((size_t)2 * 1024 * 4);
    const size_t SZ_CNT4 = alup((size_t)NBUCK4 * 4);
    const size_t SZ_CUR  = alup((size_t)N_NODES * 4);
    const size_t SZ_ACC  = alup((size_t)N_GRAPHS * 256 * 4);
    const size_t SZ_OFF  = alup((size_t)(N_NODES + 1) * 4);
    const size_t SZ_SRC  = alup((size_t)N_EDGES * 4);
    const size_t SZ_PART = alup((size_t)NBLKT * 4);
    const size_t SZ_GMS  = alup((size_t)N_GRAPHS * 4);
    size_t need = 2 * SZ_HB + SZ_SCR1 + SZ_SCR2 + SZ_G + SZ_PE + SZ_WST + SZ_BC + SZ_BIAS +
                  SZ_CNT4 + SZ_CUR + SZ_ACC + SZ_OFF + SZ_SRC + SZ_PART + 2 * SZ_GMS;
    if (ws_size < need) return;

    char* base = (char*)d_ws;
    short* hA     = (short*)base;  base += SZ_HB;
    short* hB     = (short*)base;  base += SZ_HB;
    short* scr1   = (short*)base;  base += SZ_SCR1;
    short* scr2   = (short*)base;  base += SZ_SCR2;
    float* g      = (float*)base;  base += SZ_G;
    float* peTab  = (float*)base;  base += SZ_PE;
    short* Wstack = (short*)base;  base += SZ_WST;
    short* Bcomb  = (short*)base;  base += SZ_BC;
    float* biasC  = (float*)base;  base += SZ_BIAS;
    int*   counts4= (int*)base;    base += SZ_CNT4;
    int*   cursors= (int*)base;    base += SZ_CUR;
    float* accb   = (float*)base;  base += SZ_ACC;
    int*   offs   = (int*)base;    base += SZ_OFF;
    int*   srcs   = (int*)base;    base += SZ_SRC;
    int*   partial= (int*)base;    base += SZ_PART;
    float* gm     = (float*)base;  base += SZ_GMS;
    float* gs     = (float*)base;  base += SZ_GMS;

    // ---- prep ----
    pe_kernel<<<L_POS + 1, 256, 0, stream>>>(peTab);
    cvt_wstack<<<(2 * 256 * 1024) / 256, 256, 0, stream>>>(type_w, Wstack);
    cvt_comb<<<(2 * 1024 * 512) / 256, 256, 0, stream>>>(gru_W, gru_U, Bcomb);
    cvt_bias<<<8, 256, 0, stream>>>(gru_bi, gru_br, biasC);
    {   // zero counts4 + cursors + accb (contiguous)
        int n4 = (int)((SZ_CNT4 + SZ_CUR + SZ_ACC) / 16);
        zero_int<<<(n4 + 255) / 256, 256, 0, stream>>>((int4*)counts4, n4);
    }
    histo_kernel<<<(N_EDGES + 255) / 256, 256, 0, stream>>>(edges, counts4);
    scan1<<<NBLKT, 256, 0, stream>>>(counts4, partial);
    scan2<<<1, 64, 0, stream>>>(partial, offs);
    scan3<<<NBLKT, 256, 0, stream>>>(counts4, partial, offs);
    fill_kernel<<<(N_EDGES + 255) / 256, 256, 0, stream>>>(edges, offs, cursors, srcs);
    init_h_kernel<<<N_NODES, H, 0, stream>>>(nodes, embed, peTab, hA);

    short* cur = hA;
    short* nxt = hB;
    const int steps[2] = {3, 1};
    for (int l = 0; l < 2; l++) {
        const short* WS = Wstack + (size_t)l * 256 * 1024;
        const float* Tb = type_b + (size_t)l * 4 * 256;
        const short* BC = Bcomb + (size_t)l * 1024 * 512;
        const float* Cb = biasC + (size_t)l * 1024;
        for (int s = 0; s < steps[l]; s++) {
            for (int c = 0; c < 3; c++) {
                int c0 = c0s[c], nr = nrs[c];
                int gb = (nr + 127) / 128;
                gather_kernel<<<(nr * 64 + 255) / 256, 256, 0, stream>>>(offs, srcs, cur, scr1, c0, nr);
                dim3 g1(gb, 2);
                mm_bf16<<<g1, 256, 0, stream>>>(scr1, 1024, nullptr, 0, 1024,
                                                WS, 1024, Tb, counts4, c0,
                                                scr2, 256, nr);
                dim3 g2(gb, 8);
                mm_gru<<<g2, 256, 0, stream>>>(scr2, cur + (size_t)c0 * H,
                                               BC, Cb, cur, nxt, c0, nr);
            }
            short* t = cur; cur = nxt; nxt = t;
        }
    }

    gate_kernel<<<(N_NODES * 64) / 256, 256, 0, stream>>>(cur, gate_W, gate_b, g);
    outA_kernel<<<N_GRAPHS, 256, 0, stream>>>(g, gsizes, gm, gs);
    outB_kernel<<<N_GRAPHS * OSLICE, 256, 0, stream>>>(cur, g, gsizes, gm, accb);
    outC_kernel<<<N_GRAPHS, 256, 0, stream>>>(accb, gs, out_W, out_b, out);
}

// Round 22
// 1970.319 us; speedup vs baseline: 1.2904x; 1.0954x over previous
//
#include <hip/hip_runtime.h>
#include <math.h>

#define N_NODES 100000
#define N_GRAPHS 100
#define N_EDGES 1000000
#define H 256
#define L_POS 512
#define NBUCK4 (4 * N_NODES)
#define NBLKT ((N_NODES + 255) / 256)
#define OSLICE 8

typedef short bf16x8 __attribute__((ext_vector_type(8)));
typedef float f32x4  __attribute__((ext_vector_type(4)));

__device__ inline short f2bf(float f) {
    union { float f; unsigned u; } v; v.f = f;
    unsigned r = (v.u + 0x7FFF + ((v.u >> 16) & 1)) >> 16;
    return (short)r;
}
__device__ inline float bf2f(unsigned short u) {
    union { unsigned u; float f; } v; v.u = ((unsigned)u) << 16;
    return v.f;
}

// fast transcendentals (hw v_exp_f32 path)
__device__ inline float fsigm(float x) { return 1.0f / (1.0f + __expf(-x)); }
__device__ inline float ftanh(float x) {
    float t = __expf(-2.0f * fabsf(x));
    float y = 1.0f - 2.0f * t / (1.0f + t);
    return copysignf(y, x);
}

// async global->LDS, 16B per lane; lds dest = wave-uniform base + lane*16
__device__ inline void async16(short* l, const short* g) {
    __builtin_amdgcn_global_load_lds(
        (const __attribute__((address_space(1))) void*)g,
        (__attribute__((address_space(3))) void*)l, 16, 0, 0);
}

// ---------------- zero ints ----------------
__global__ void zero_int(int4* __restrict__ p, int n4)
{
    int i = blockIdx.x * 256 + threadIdx.x;
    if (i < n4) p[i] = make_int4(0, 0, 0, 0);
}

// ---------------- PE table ----------------
__global__ void pe_kernel(float* __restrict__ pe)
{
    int p = blockIdx.x;
    int j = threadIdx.x;
    float v = 0.0f;
    if (p > 0) {
        float pos = (float)(p - 1);
        float denom = powf(10000.0f, 2.0f * (float)j / (float)H);
        float ang = pos / denom;
        v = (j & 1) ? cosf(ang) : sinf(ang);
    }
    pe[p * H + j] = v;
}

// ---------------- init h (bf16) ----------------
__global__ void init_h_kernel(const int* __restrict__ nodes,
                              const float* __restrict__ embed,
                              const float* __restrict__ pe,
                              short* __restrict__ h)
{
    int n = blockIdx.x;
    int j = threadIdx.x;
    int tok = nodes[n];
    int p = nodes[N_NODES + n];
    if (p > L_POS) p = L_POS;
    h[(size_t)n * H + j] = f2bf(embed[(size_t)tok * H + j] + pe[p * H + j]);
}

// ---------------- weight prep ----------------
__global__ void cvt_wstack(const float* __restrict__ w, short* __restrict__ wt)
{
    int idx = blockIdx.x * 256 + threadIdx.x;
    if (idx >= 2 * 256 * 1024) return;
    int l = idx / (256 * 1024);
    int rem = idx % (256 * 1024);
    int n = rem >> 10, k = rem & 1023;
    int t = k >> 8, kk = k & 255;
    wt[idx] = f2bf(w[(((size_t)(l * 4 + t)) * 256 + kk) * 256 + n]);
}
// permuted column for GRU-fused epilogue: gate g, feature f -> p
__host__ __device__ inline int permcol(int g, int f)
{
    return ((f >> 4) << 6) + (g << 4) + (f & 15);
}
__global__ void cvt_comb(const float* __restrict__ W, const float* __restrict__ U,
                         short* __restrict__ B)
{
    int idx = blockIdx.x * 256 + threadIdx.x;
    if (idx >= 2 * 1024 * 512) return;
    int l = idx / (1024 * 512);
    int rem = idx % (1024 * 512);
    int n = rem >> 9, k = rem & 511;
    float v = 0.0f;
    if (n < 512) {
        v = (k < 256) ? W[((size_t)l * 256 + k) * 768 + n]
                      : U[((size_t)l * 256 + (k - 256)) * 768 + n];
    } else if (n < 768) {
        if (k < 256) v = W[((size_t)l * 256 + k) * 768 + n];
    } else {
        if (k >= 256) v = U[((size_t)l * 256 + (k - 256)) * 768 + (n - 256)];
    }
    int g = n >> 8, f = n & 255;
    B[((size_t)l * 1024 + permcol(g, f)) * 512 + k] = f2bf(v);
}
__global__ void cvt_bias(const float* __restrict__ bi, const float* __restrict__ br,
                         float* __restrict__ biasC)
{
    int idx = blockIdx.x * 256 + threadIdx.x;
    if (idx >= 2048) return;
    int l = idx >> 10, n = idx & 1023;
    float v;
    if (n < 512)      v = bi[l * 768 + n] + br[l * 768 + n];
    else if (n < 768) v = bi[l * 768 + n];
    else              v = br[l * 768 + (n - 256)];
    int g = n >> 8, f = n & 255;
    biasC[(size_t)l * 1024 + permcol(g, f)] = v;
}

// ---------------- CSR build ----------------
__global__ void histo_kernel(const int* __restrict__ edges, int* __restrict__ counts4)
{
    int e = blockIdx.x * 256 + threadIdx.x;
    if (e >= N_EDGES) return;
    int t = edges[e * 3];
    int tg = edges[e * 3 + 2];
    atomicAdd(&counts4[t * N_NODES + tg], 1);
}
__device__ inline int cnt_tgt(const int* counts4, int i)
{
    return counts4[i] + counts4[N_NODES + i] + counts4[2 * N_NODES + i] + counts4[3 * N_NODES + i];
}
__global__ void scan1(const int* __restrict__ counts4, int* __restrict__ partial)
{
    __shared__ int s[256];
    int i = blockIdx.x * 256 + threadIdx.x;
    s[threadIdx.x] = (i < N_NODES) ? cnt_tgt(counts4, i) : 0;
    __syncthreads();
    for (int off = 128; off > 0; off >>= 1) {
        if (threadIdx.x < off) s[threadIdx.x] += s[threadIdx.x + off];
        __syncthreads();
    }
    if (threadIdx.x == 0) partial[blockIdx.x] = s[0];
}
__global__ void scan2(int* __restrict__ partial, int* __restrict__ offs)
{
    if (threadIdx.x == 0 && blockIdx.x == 0) {
        int run = 0;
        for (int i = 0; i < NBLKT; i++) { int v = partial[i]; partial[i] = run; run += v; }
        offs[N_NODES] = run;
    }
}
__global__ void scan3(const int* __restrict__ counts4, const int* __restrict__ partial,
                      int* __restrict__ offs)
{
    __shared__ int s[256];
    int i = blockIdx.x * 256 + threadIdx.x;
    int v = (i < N_NODES) ? cnt_tgt(counts4, i) : 0;
    s[threadIdx.x] = v;
    __syncthreads();
    for (int off = 1; off < 256; off <<= 1) {
        int add = (threadIdx.x >= off) ? s[threadIdx.x - off] : 0;
        __syncthreads();
        s[threadIdx.x] += add;
        __syncthreads();
    }
    if (i < N_NODES) offs[i] = partial[blockIdx.x] + s[threadIdx.x] - v;
}
__global__ void fill_kernel(const int* __restrict__ edges, const int* __restrict__ offs,
                            int* __restrict__ cursors, int* __restrict__ srcs)
{
    int e = blockIdx.x * 256 + threadIdx.x;
    if (e >= N_EDGES) return;
    int t = edges[e * 3];
    int s = edges[e * 3 + 1];
    int tg = edges[e * 3 + 2];
    int p = atomicAdd(&cursors[tg], 1);
    srcs[offs[tg] + p] = s | (t << 17);
}

// ---- gather: deep-MLP batching (8 row-loads in flight per wave) ----
__global__ __launch_bounds__(256) void gather_kernel(
    const int* __restrict__ offs, const int* __restrict__ srcs,
    const short* __restrict__ h, short* __restrict__ gath4, int c0, int nr)
{
    int w = (blockIdx.x * 256 + threadIdx.x) >> 6;
    int lane = threadIdx.x & 63;
    if (w >= nr) return;
    int tgt = c0 + w;
    int col = lane * 4;
    int e0 = offs[tgt], e1 = offs[tgt + 1];
    float4 a0 = make_float4(0.f,0.f,0.f,0.f), a1 = a0, a2 = a0, a3 = a0;

    #define ACCUM(V, PK) do {                                                  \
        float4 vv = make_float4(bf2f((unsigned short)((PK).x & 0xFFFF)),       \
                                bf2f((unsigned short)((PK).x >> 16)),          \
                                bf2f((unsigned short)((PK).y & 0xFFFF)),       \
                                bf2f((unsigned short)((PK).y >> 16)));         \
        int tt = (V) >> 17;                                                    \
        switch (tt) {                                                          \
        case 0: a0.x += vv.x; a0.y += vv.y; a0.z += vv.z; a0.w += vv.w; break; \
        case 1: a1.x += vv.x; a1.y += vv.y; a1.z += vv.z; a1.w += vv.w; break; \
        case 2: a2.x += vv.x; a2.y += vv.y; a2.z += vv.z; a2.w += vv.w; break; \
        default: a3.x += vv.x; a3.y += vv.y; a3.z += vv.z; a3.w += vv.w; }     \
    } while (0)

    int e = e0;
    for (; e + 8 <= e1; e += 8) {
        int v[8];
        #pragma unroll
        for (int i = 0; i < 8; i++)
            v[i] = __builtin_amdgcn_readfirstlane(srcs[e + i]);
        uint2 p[8];
        #pragma unroll
        for (int i = 0; i < 8; i++)
            p[i] = *(const uint2*)(h + (size_t)(v[i] & 0x1FFFF) * H + col);
        #pragma unroll
        for (int i = 0; i < 8; i++)
            ACCUM(v[i], p[i]);
    }
    if (e + 4 <= e1) {
        int v[4];
        #pragma unroll
        for (int i = 0; i < 4; i++)
            v[i] = __builtin_amdgcn_readfirstlane(srcs[e + i]);
        uint2 p[4];
        #pragma unroll
        for (int i = 0; i < 4; i++)
            p[i] = *(const uint2*)(h + (size_t)(v[i] & 0x1FFFF) * H + col);
        #pragma unroll
        for (int i = 0; i < 4; i++)
            ACCUM(v[i], p[i]);
        e += 4;
    }
    for (; e < e1; e++) {
        int v0 = __builtin_amdgcn_readfirstlane(srcs[e]);
        uint2 p0 = *(const uint2*)(h + (size_t)(v0 & 0x1FFFF) * H + col);
        ACCUM(v0, p0);
    }
    #undef ACCUM

    short* dst = gath4 + (size_t)w * 1024 + col;
    #define PACK(A) make_uint2( \
        ((unsigned)(unsigned short)f2bf((A).x)) | (((unsigned)(unsigned short)f2bf((A).y)) << 16), \
        ((unsigned)(unsigned short)f2bf((A).z)) | (((unsigned)(unsigned short)f2bf((A).w)) << 16))
    *(uint2*)(dst)       = PACK(a0);
    *(uint2*)(dst + 256) = PACK(a1);
    *(uint2*)(dst + 512) = PACK(a2);
    *(uint2*)(dst + 768) = PACK(a3);
    #undef PACK
}

// ---- mm1: bf16 MFMA matmul, async dbuf, one barrier/tile, XCD-aware swizzle ----
// grid must be (8, nNb*mpx) where nNb = 1<<nbShift N-blocks, mpx = ceil(nMb/8).
__global__ __launch_bounds__(256) void mm_bf16(
    const short* __restrict__ A0, int s0, const short* __restrict__ A1, int s1, int K0,
    const short* __restrict__ BT, int Ktot,
    const float* __restrict__ bias,
    const int* __restrict__ cnt, int c0,
    short* __restrict__ C, int ldc, int nrows, int nbShift)
{
    __shared__ short As[2][128 * 32];
    __shared__ short Bs[2][128 * 32];
    const int tid = threadIdx.x;
    const int nMb = (nrows + 127) >> 7;
    const int mpx = (nMb + 7) >> 3;
    const int lin = blockIdx.x + blockIdx.y * 8;
    const int xcd = lin & 7;
    const int idx = lin >> 3;
    const int bmi = xcd * mpx + (idx >> nbShift);
    if (bmi >= nMb) return;
    const int bm = bmi << 7;
    const int bn = (idx & ((1 << nbShift) - 1)) << 7;
    const int lane = tid & 63;
    const int wave = tid >> 6;
    const int wm = (wave >> 1) * 64;
    const int wn = (wave & 1) * 64;
    const int q = lane >> 4;
    const int r16 = lane & 15;

    f32x4 acc[4][4];
    #pragma unroll
    for (int i = 0; i < 4; i++)
        #pragma unroll
        for (int j = 0; j < 4; j++)
            acc[i][j] = (f32x4){0.f, 0.f, 0.f, 0.f};

    const int seg0 = wave * 2;
    const int rloc0 = seg0 * 16 + (lane >> 2);
    const int rloc1 = rloc0 + 16;
    const int un = (lane & 3) * 8;
    int ga0 = bm + rloc0; if (ga0 >= nrows) ga0 = nrows - 1;
    int ga1 = bm + rloc1; if (ga1 >= nrows) ga1 = nrows - 1;

    const short* b0p = BT + (size_t)(bn + rloc0) * Ktot + un;
    const short* b1p = BT + (size_t)(bn + rloc1) * Ktot + un;
    const short* a0p = A0 + (size_t)ga0 * s0 + un;
    const short* a1p = A0 + (size_t)ga1 * s0 + un;
    const int nT = Ktot >> 5;

    async16(&As[0][seg0 * 512], a0p);
    async16(&As[0][(seg0 + 1) * 512], a1p);
    async16(&Bs[0][seg0 * 512], b0p);
    async16(&Bs[0][(seg0 + 1) * 512], b1p);
    a0p += 32; a1p += 32; b0p += 32; b1p += 32;

    int buf = 0;
    for (int i = 0; i < nT; i++) {
        __syncthreads();
        if (i + 1 < nT) {
            int nb = buf ^ 1;
            async16(&As[nb][seg0 * 512], a0p);
            async16(&As[nb][(seg0 + 1) * 512], a1p);
            async16(&Bs[nb][seg0 * 512], b0p);
            async16(&Bs[nb][(seg0 + 1) * 512], b1p);
            a0p += 32; a1p += 32; b0p += 32; b1p += 32;
        }
        bf16x8 af[4], bfr[4];
        #pragma unroll
        for (int mt = 0; mt < 4; mt++)
            af[mt] = *(const bf16x8*)&As[buf][(wm + mt * 16 + r16) * 32 + q * 8];
        #pragma unroll
        for (int nt = 0; nt < 4; nt++)
            bfr[nt] = *(const bf16x8*)&Bs[buf][(wn + nt * 16 + r16) * 32 + q * 8];
        #pragma unroll
        for (int mt = 0; mt < 4; mt++)
            #pragma unroll
            for (int nt = 0; nt < 4; nt++)
                acc[mt][nt] = __builtin_amdgcn_mfma_f32_16x16x32_bf16(af[mt], bfr[nt], acc[mt][nt], 0, 0, 0);
        buf ^= 1;
    }

    #pragma unroll
    for (int mt = 0; mt < 4; mt++) {
        #pragma unroll
        for (int reg = 0; reg < 4; reg++) {
            int row = bm + wm + mt * 16 + q * 4 + reg;
            if (row >= nrows) continue;
            #pragma unroll
            for (int nt = 0; nt < 4; nt++) {
                int col = bn + wn + nt * 16 + r16;
                float v = acc[mt][nt][reg];
                if (cnt) {
                    #pragma unroll
                    for (int t = 0; t < 4; t++)
                        v += (float)cnt[t * N_NODES + c0 + row] * bias[t * 256 + col];
                } else {
                    v += bias[col];
                }
                C[(size_t)row * ldc + col] = f2bf(v);
            }
        }
    }
}

// ---- mm2 fused: S-matmul + GRU epilogue, async dbuf, XCD-aware swizzle ----
// grid (8, 8*mpx); N fixed at 1024 (8 N-blocks).
__global__ __launch_bounds__(256) void mm_gru(
    const short* __restrict__ A0, const short* __restrict__ A1,
    const short* __restrict__ BT,
    const float* __restrict__ bias,
    const short* __restrict__ hOld, short* __restrict__ hNew,
    int c0, int nrows)
{
    __shared__ short As[2][128 * 32];
    __shared__ short Bs[2][128 * 32];
    const int tid = threadIdx.x;
    const int nMb = (nrows + 127) >> 7;
    const int mpx = (nMb + 7) >> 3;
    const int lin = blockIdx.x + blockIdx.y * 8;
    const int xcd = lin & 7;
    const int idx = lin >> 3;
    const int bmi = xcd * mpx + (idx >> 3);
    if (bmi >= nMb) return;
    const int bm = bmi << 7;
    const int bn = (idx & 7) << 7;
    const int lane = tid & 63;
    const int wave = tid >> 6;
    const int wm = (wave >> 1) * 64;
    const int wn = (wave & 1) * 64;
    const int q = lane >> 4;
    const int r16 = lane & 15;
    const int Ktot = 512;

    f32x4 acc[4][4];
    #pragma unroll
    for (int i = 0; i < 4; i++)
        #pragma unroll
        for (int j = 0; j < 4; j++)
            acc[i][j] = (f32x4){0.f, 0.f, 0.f, 0.f};

    const int seg0 = wave * 2;
    const int rloc0 = seg0 * 16 + (lane >> 2);
    const int rloc1 = rloc0 + 16;
    const int un = (lane & 3) * 8;
    int ga0 = bm + rloc0; if (ga0 >= nrows) ga0 = nrows - 1;
    int ga1 = bm + rloc1; if (ga1 >= nrows) ga1 = nrows - 1;

    const short* b0p = BT + (size_t)(bn + rloc0) * Ktot + un;
    const short* b1p = BT + (size_t)(bn + rloc1) * Ktot + un;
    const short* a0p = A0 + (size_t)ga0 * 256 + un;
    const short* a1p = A0 + (size_t)ga1 * 256 + un;

    async16(&As[0][seg0 * 512], a0p);
    async16(&As[0][(seg0 + 1) * 512], a1p);
    async16(&Bs[0][seg0 * 512], b0p);
    async16(&Bs[0][(seg0 + 1) * 512], b1p);
    a0p += 32; a1p += 32; b0p += 32; b1p += 32;

    int buf = 0;
    for (int i = 0; i < 16; i++) {
        __syncthreads();
        if (i + 1 < 16) {
            int nb = buf ^ 1;
            async16(&As[nb][seg0 * 512], a0p);
            async16(&As[nb][(seg0 + 1) * 512], a1p);
            async16(&Bs[nb][seg0 * 512], b0p);
            async16(&Bs[nb][(seg0 + 1) * 512], b1p);
            if (i + 2 == 8) {
                a0p = A1 + (size_t)ga0 * 256 + un;
                a1p = A1 + (size_t)ga1 * 256 + un;
            } else {
                a0p += 32; a1p += 32;
            }
            b0p += 32; b1p += 32;
        }
        bf16x8 af[4], bfr[4];
        #pragma unroll
        for (int mt = 0; mt < 4; mt++)
            af[mt] = *(const bf16x8*)&As[buf][(wm + mt * 16 + r16) * 32 + q * 8];
        #pragma unroll
        for (int nt = 0; nt < 4; nt++)
            bfr[nt] = *(const bf16x8*)&Bs[buf][(wn + nt * 16 + r16) * 32 + q * 8];
        #pragma unroll
        for (int mt = 0; mt < 4; mt++)
            #pragma unroll
            for (int nt = 0; nt < 4; nt++)
                acc[mt][nt] = __builtin_amdgcn_mfma_f32_16x16x32_bf16(af[mt], bfr[nt], acc[mt][nt], 0, 0, 0);
        buf ^= 1;
    }

    // GRU epilogue (fast transcendentals)
    const int f = ((bn + wn) >> 2) + r16;
    const float bz = bias[bn + wn + 0 * 16 + r16];
    const float br_ = bias[bn + wn + 1 * 16 + r16];
    const float bx = bias[bn + wn + 2 * 16 + r16];
    const float bh = bias[bn + wn + 3 * 16 + r16];
    #pragma unroll
    for (int mt = 0; mt < 4; mt++) {
        #pragma unroll
        for (int reg = 0; reg < 4; reg++) {
            int row = bm + wm + mt * 16 + q * 4 + reg;
            if (row >= nrows) continue;
            float vz = acc[mt][0][reg] + bz;
            float vr = acc[mt][1][reg] + br_;
            float vx = acc[mt][2][reg] + bx;
            float vh = acc[mt][3][reg] + bh;
            size_t idx2 = (size_t)(c0 + row) * H + f;
            float hv = bf2f((unsigned short)hOld[idx2]);
            float z = fsigm(vz);
            float r = fsigm(vr);
            float cand = ftanh(vx + r * vh);
            hNew[idx2] = f2bf(z * hv + (1.0f - z) * cand);
        }
    }
}

// ---------------- gate logits ----------------
__global__ __launch_bounds__(256) void gate_kernel(const short* __restrict__ h,
                                                   const float* __restrict__ gW,
                                                   const float* __restrict__ gb,
                                                   float* __restrict__ g)
{
    int tid = blockIdx.x * 256 + threadIdx.x;
    int n = tid >> 6;
    if (n >= N_NODES) return;
    int lane = tid & 63;
    uint2 pk = *(const uint2*)(h + (size_t)n * H + lane * 4);
    float4 w = *(const float4*)(gW + lane * 4);
    float s = bf2f((unsigned short)(pk.x & 0xFFFF)) * w.x
            + bf2f((unsigned short)(pk.x >> 16))    * w.y
            + bf2f((unsigned short)(pk.y & 0xFFFF)) * w.z
            + bf2f((unsigned short)(pk.y >> 16))    * w.w;
    #pragma unroll
    for (int off = 32; off > 0; off >>= 1)
        s += __shfl_down(s, off);
    if (lane == 0) g[n] = s + gb[0];
}

// ---------------- readout phase A: per-graph max & sumexp ----------------
__global__ __launch_bounds__(256) void outA_kernel(const float* __restrict__ g,
                                                   const int* __restrict__ sizes,
                                                   float* __restrict__ gm,
                                                   float* __restrict__ gs)
{
    __shared__ float red[256];
    int gid = blockIdx.x;
    int tid = threadIdx.x;
    int start = 0, end = 0;
    {
        int c = 0;
        for (int i = 0; i < N_GRAPHS; i++) {
            int sz = sizes[i];
            if (i == gid) { start = c; end = c + sz; }
            c += sz;
        }
    }
    float m = -INFINITY;
    for (int n = start + tid; n < end; n += 256) m = fmaxf(m, g[n]);
    red[tid] = m; __syncthreads();
    for (int s = 128; s > 0; s >>= 1) {
        if (tid < s) red[tid] = fmaxf(red[tid], red[tid + s]);
        __syncthreads();
    }
    m = red[0]; __syncthreads();
    float s_ = 0.0f;
    for (int n = start + tid; n < end; n += 256) s_ += __expf(g[n] - m);
    red[tid] = s_; __syncthreads();
    for (int s = 128; s > 0; s >>= 1) {
        if (tid < s) red[tid] += red[tid + s];
        __syncthreads();
    }
    if (tid == 0) { gm[gid] = m; gs[gid] = red[0]; }
}

// ---------------- readout phase B: sliced e-weighted feature sums ----------------
__global__ __launch_bounds__(256) void outB_kernel(const short* __restrict__ h,
                                                   const float* __restrict__ g,
                                                   const int* __restrict__ sizes,
                                                   const float* __restrict__ gm,
                                                   float* __restrict__ accb)
{
    __shared__ float red4[4][256];
    int gid = blockIdx.x / OSLICE;
    int si = blockIdx.x % OSLICE;
    int tid = threadIdx.x;
    int wave = tid >> 6;
    int lane = tid & 63;
    int start = 0, end = 0;
    {
        int c = 0;
        for (int i = 0; i < N_GRAPHS; i++) {
            int sz = sizes[i];
            if (i == gid) { start = c; end = c + sz; }
            c += sz;
        }
    }
    float m = gm[gid];
    float a0 = 0.f, a1 = 0.f, a2 = 0.f, a3 = 0.f;
    for (int n = start + si * 4 + wave; n < end; n += OSLICE * 4) {
        float e = __expf(g[n] - m);
        uint2 pk = *(const uint2*)(h + (size_t)n * H + lane * 4);
        a0 += e * bf2f((unsigned short)(pk.x & 0xFFFF));
        a1 += e * bf2f((unsigned short)(pk.x >> 16));
        a2 += e * bf2f((unsigned short)(pk.y & 0xFFFF));
        a3 += e * bf2f((unsigned short)(pk.y >> 16));
    }
    red4[wave][lane * 4 + 0] = a0;
    red4[wave][lane * 4 + 1] = a1;
    red4[wave][lane * 4 + 2] = a2;
    red4[wave][lane * 4 + 3] = a3;
    __syncthreads();
    float acc = red4[0][tid] + red4[1][tid] + red4[2][tid] + red4[3][tid];
    unsafeAtomicAdd(&accb[(size_t)gid * 256 + tid], acc);
}

// ---------------- readout phase C: project to outputs ----------------
__global__ __launch_bounds__(256) void outC_kernel(const float* __restrict__ accb,
                                                   const float* __restrict__ gs,
                                                   const float* __restrict__ outW,
                                                   const float* __restrict__ outBs,
                                                   float* __restrict__ out)
{
    __shared__ float red[256];
    int gid = blockIdx.x;
    int tid = threadIdx.x;
    float ssum = gs[gid];
    float inv = 1.0f / (ssum + 1e-16f);
    float a = accb[(size_t)gid * 256 + tid];
    for (int c = 0; c < 2; c++) {
        red[tid] = a * outW[tid * 2 + c];
        __syncthreads();
        for (int s = 128; s > 0; s >>= 1) {
            if (tid < s) red[tid] += red[tid + s];
            __syncthreads();
        }
        if (tid == 0) out[gid * 2 + c] = red[0] * inv + outBs[c] * (ssum * inv);
        __syncthreads();
    }
}

static inline size_t alup(size_t x) { return (x + 255) & ~(size_t)255; }

extern "C" void kernel_launch(void* const* d_in, const int* in_sizes, int n_in,
                              void* d_out, int out_size, void* d_ws, size_t ws_size,
                              hipStream_t stream)
{
    const int*   nodes  = (const int*)d_in[0];
    const int*   gsizes = (const int*)d_in[1];
    const int*   edges  = (const int*)d_in[2];
    const float* embed  = (const float*)d_in[3];
    const float* type_w = (const float*)d_in[4];
    const float* type_b = (const float*)d_in[5];
    const float* gru_W  = (const float*)d_in[6];
    const float* gru_U  = (const float*)d_in[7];
    const float* gru_bi = (const float*)d_in[8];
    const float* gru_br = (const float*)d_in[9];
    const float* gate_W = (const float*)d_in[10];
    const float* gate_b = (const float*)d_in[11];
    const float* out_W  = (const float*)d_in[12];
    const float* out_b  = (const float*)d_in[13];
    float* out = (float*)d_out;

    const int CHMAX = 33334;
    const int c0s[3] = {0, 33334, 66667};
    const int nrs[3] = {33334, 33333, 33333};

    // ---- workspace layout (bytes), total ~199 MB ----
    const size_t SZ_HB   = alup((size_t)N_NODES * H * 2);
    const size_t SZ_SCR1 = alup((size_t)CHMAX * 1024 * 2);
    const size_t SZ_SCR2 = alup((size_t)CHMAX * 256 * 2);
    const size_t SZ_G    = alup((size_t)N_NODES * 4);
    const size_t SZ_PE   = alup((size_t)(L_POS + 1) * H * 4);
    const size_t SZ_WST  = alup((size_t)2 * 256 * 1024 * 2);
    const size_t SZ_BC   = alup((size_t)2 * 1024 * 512 * 2);
    const size_t SZ_BIAS = alup((size_t)2 * 1024 * 4);
    const size_t SZ_CNT4 = alup((size_t)NBUCK4 * 4);
    const size_t SZ_CUR  = alup((size_t)N_NODES * 4);
    const size_t SZ_ACC  = alup((size_t)N_GRAPHS * 256 * 4);
    const size_t SZ_OFF  = alup((size_t)(N_NODES + 1) * 4);
    const size_t SZ_SRC  = alup((size_t)N_EDGES * 4);
    const size_t SZ_PART = alup((size_t)NBLKT * 4);
    const size_t SZ_GMS  = alup((size_t)N_GRAPHS * 4);
    size_t need = 2 * SZ_HB + SZ_SCR1 + SZ_SCR2 + SZ_G + SZ_PE + SZ_WST + SZ_BC + SZ_BIAS +
                  SZ_CNT4 + SZ_CUR + SZ_ACC + SZ_OFF + SZ_SRC + SZ_PART + 2 * SZ_GMS;
    if (ws_size < need) return;

    char* base = (char*)d_ws;
    short* hA     = (short*)base;  base += SZ_HB;
    short* hB     = (short*)base;  base += SZ_HB;
    short* scr1   = (short*)base;  base += SZ_SCR1;
    short* scr2   = (short*)base;  base += SZ_SCR2;
    float* g      = (float*)base;  base += SZ_G;
    float* peTab  = (float*)base;  base += SZ_PE;
    short* Wstack = (short*)base;  base += SZ_WST;
    short* Bcomb  = (short*)base;  base += SZ_BC;
    float* biasC  = (float*)base;  base += SZ_BIAS;
    int*   counts4= (int*)base;    base += SZ_CNT4;
    int*   cursors= (int*)base;    base += SZ_CUR;
    float* accb   = (float*)base;  base += SZ_ACC;
    int*   offs   = (int*)base;    base += SZ_OFF;
    int*   srcs   = (int*)base;    base += SZ_SRC;
    int*   partial= (int*)base;    base += SZ_PART;
    float* gm     = (float*)base;  base += SZ_GMS;
    float* gs     = (float*)base;  base += SZ_GMS;

    // ---- prep ----
    pe_kernel<<<L_POS + 1, 256, 0, stream>>>(peTab);
    cvt_wstack<<<(2 * 256 * 1024) / 256, 256, 0, stream>>>(type_w, Wstack);
    cvt_comb<<<(2 * 1024 * 512) / 256, 256, 0, stream>>>(gru_W, gru_U, Bcomb);
    cvt_bias<<<8, 256, 0, stream>>>(gru_bi, gru_br, biasC);
    {   // zero counts4 + cursors + accb (contiguous)
        int n4 = (int)((SZ_CNT4 + SZ_CUR + SZ_ACC) / 16);
        zero_int<<<(n4 + 255) / 256, 256, 0, stream>>>((int4*)counts4, n4);
    }
    histo_kernel<<<(N_EDGES + 255) / 256, 256, 0, stream>>>(edges, counts4);
    scan1<<<NBLKT, 256, 0, stream>>>(counts4, partial);
    scan2<<<1, 64, 0, stream>>>(partial, offs);
    scan3<<<NBLKT, 256, 0, stream>>>(counts4, partial, offs);
    fill_kernel<<<(N_EDGES + 255) / 256, 256, 0, stream>>>(edges, offs, cursors, srcs);
    init_h_kernel<<<N_NODES, H, 0, stream>>>(nodes, embed, peTab, hA);

    short* cur = hA;
    short* nxt = hB;
    const int steps[2] = {3, 1};
    for (int l = 0; l < 2; l++) {
        const short* WS = Wstack + (size_t)l * 256 * 1024;
        const float* Tb = type_b + (size_t)l * 4 * 256;
        const short* BC = Bcomb + (size_t)l * 1024 * 512;
        const float* Cb = biasC + (size_t)l * 1024;
        for (int s = 0; s < steps[l]; s++) {
            for (int c = 0; c < 3; c++) {
                int c0 = c0s[c], nr = nrs[c];
                int nMb = (nr + 127) / 128;
                int mpx = (nMb + 7) / 8;
                gather_kernel<<<(nr * 64 + 255) / 256, 256, 0, stream>>>(offs, srcs, cur, scr1, c0, nr);
                dim3 g1(8, 2 * mpx);   // nNb=2 (nbShift=1)
                mm_bf16<<<g1, 256, 0, stream>>>(scr1, 1024, nullptr, 0, 1024,
                                                WS, 1024, Tb, counts4, c0,
                                                scr2, 256, nr, 1);
                dim3 g2(8, 8 * mpx);   // nNb=8
                mm_gru<<<g2, 256, 0, stream>>>(scr2, cur + (size_t)c0 * H,
                                               BC, Cb, cur, nxt, c0, nr);
            }
            short* t = cur; cur = nxt; nxt = t;
        }
    }

    gate_kernel<<<(N_NODES * 64) / 256, 256, 0, stream>>>(cur, gate_W, gate_b, g);
    outA_kernel<<<N_GRAPHS, 256, 0, stream>>>(g, gsizes, gm, gs);
    outB_kernel<<<N_GRAPHS * OSLICE, 256, 0, stream>>>(cur, g, gsizes, gm, accb);
    outC_kernel<<<N_GRAPHS, 256, 0, stream>>>(accb, gs, out_W, out_b, out);
}

// Round 23
// 1932.654 us; speedup vs baseline: 1.3155x; 1.0195x over previous
//
#include <hip/hip_runtime.h>
#include <math.h>

#define N_NODES 100000
#define N_GRAPHS 100
#define N_EDGES 1000000
#define H 256
#define L_POS 512
#define NBUCK4 (4 * N_NODES)
#define NBLKT ((N_NODES + 255) / 256)
#define OSLICE 8

typedef short bf16x8 __attribute__((ext_vector_type(8)));
typedef float f32x4  __attribute__((ext_vector_type(4)));

__device__ inline short f2bf(float f) {
    union { float f; unsigned u; } v; v.f = f;
    unsigned r = (v.u + 0x7FFF + ((v.u >> 16) & 1)) >> 16;
    return (short)r;
}
__device__ inline float bf2f(unsigned short u) {
    union { unsigned u; float f; } v; v.u = ((unsigned)u) << 16;
    return v.f;
}

// fast transcendentals (hw v_exp_f32 path)
__device__ inline float fsigm(float x) { return 1.0f / (1.0f + __expf(-x)); }
__device__ inline float ftanh(float x) {
    float t = __expf(-2.0f * fabsf(x));
    float y = 1.0f - 2.0f * t / (1.0f + t);
    return copysignf(y, x);
}

// async global->LDS, 16B per lane; lds dest = wave-uniform base + lane*16
__device__ inline void async16(short* l, const short* g) {
    __builtin_amdgcn_global_load_lds(
        (const __attribute__((address_space(1))) void*)g,
        (__attribute__((address_space(3))) void*)l, 16, 0, 0);
}

// ---------------- zero ints ----------------
__global__ void zero_int(int4* __restrict__ p, int n4)
{
    int i = blockIdx.x * 256 + threadIdx.x;
    if (i < n4) p[i] = make_int4(0, 0, 0, 0);
}

// ---------------- PE table ----------------
__global__ void pe_kernel(float* __restrict__ pe)
{
    int p = blockIdx.x;
    int j = threadIdx.x;
    float v = 0.0f;
    if (p > 0) {
        float pos = (float)(p - 1);
        float denom = powf(10000.0f, 2.0f * (float)j / (float)H);
        float ang = pos / denom;
        v = (j & 1) ? cosf(ang) : sinf(ang);
    }
    pe[p * H + j] = v;
}

// ---------------- init h (bf16) ----------------
__global__ void init_h_kernel(const int* __restrict__ nodes,
                              const float* __restrict__ embed,
                              const float* __restrict__ pe,
                              short* __restrict__ h)
{
    int n = blockIdx.x;
    int j = threadIdx.x;
    int tok = nodes[n];
    int p = nodes[N_NODES + n];
    if (p > L_POS) p = L_POS;
    h[(size_t)n * H + j] = f2bf(embed[(size_t)tok * H + j] + pe[p * H + j]);
}

// ---------------- weight prep ----------------
__global__ void cvt_wstack(const float* __restrict__ w, short* __restrict__ wt)
{
    int idx = blockIdx.x * 256 + threadIdx.x;
    if (idx >= 2 * 256 * 1024) return;
    int l = idx / (256 * 1024);
    int rem = idx % (256 * 1024);
    int n = rem >> 10, k = rem & 1023;
    int t = k >> 8, kk = k & 255;
    wt[idx] = f2bf(w[(((size_t)(l * 4 + t)) * 256 + kk) * 256 + n]);
}
// permuted column for GRU-fused epilogue: gate g, feature f -> p
__host__ __device__ inline int permcol(int g, int f)
{
    return ((f >> 4) << 6) + (g << 4) + (f & 15);
}
__global__ void cvt_comb(const float* __restrict__ W, const float* __restrict__ U,
                         short* __restrict__ B)
{
    int idx = blockIdx.x * 256 + threadIdx.x;
    if (idx >= 2 * 1024 * 512) return;
    int l = idx / (1024 * 512);
    int rem = idx % (1024 * 512);
    int n = rem >> 9, k = rem & 511;
    float v = 0.0f;
    if (n < 512) {
        v = (k < 256) ? W[((size_t)l * 256 + k) * 768 + n]
                      : U[((size_t)l * 256 + (k - 256)) * 768 + n];
    } else if (n < 768) {
        if (k < 256) v = W[((size_t)l * 256 + k) * 768 + n];
    } else {
        if (k >= 256) v = U[((size_t)l * 256 + (k - 256)) * 768 + (n - 256)];
    }
    int g = n >> 8, f = n & 255;
    B[((size_t)l * 1024 + permcol(g, f)) * 512 + k] = f2bf(v);
}
__global__ void cvt_bias(const float* __restrict__ bi, const float* __restrict__ br,
                         float* __restrict__ biasC)
{
    int idx = blockIdx.x * 256 + threadIdx.x;
    if (idx >= 2048) return;
    int l = idx >> 10, n = idx & 1023;
    float v;
    if (n < 512)      v = bi[l * 768 + n] + br[l * 768 + n];
    else if (n < 768) v = bi[l * 768 + n];
    else              v = br[l * 768 + (n - 256)];
    int g = n >> 8, f = n & 255;
    biasC[(size_t)l * 1024 + permcol(g, f)] = v;
}

// ---------------- CSR build ----------------
__global__ void histo_kernel(const int* __restrict__ edges, int* __restrict__ counts4)
{
    int e = blockIdx.x * 256 + threadIdx.x;
    if (e >= N_EDGES) return;
    int t = edges[e * 3];
    int tg = edges[e * 3 + 2];
    atomicAdd(&counts4[t * N_NODES + tg], 1);
}
__device__ inline int cnt_tgt(const int* counts4, int i)
{
    return counts4[i] + counts4[N_NODES + i] + counts4[2 * N_NODES + i] + counts4[3 * N_NODES + i];
}
__global__ void scan1(const int* __restrict__ counts4, int* __restrict__ partial)
{
    __shared__ int s[256];
    int i = blockIdx.x * 256 + threadIdx.x;
    s[threadIdx.x] = (i < N_NODES) ? cnt_tgt(counts4, i) : 0;
    __syncthreads();
    for (int off = 128; off > 0; off >>= 1) {
        if (threadIdx.x < off) s[threadIdx.x] += s[threadIdx.x + off];
        __syncthreads();
    }
    if (threadIdx.x == 0) partial[blockIdx.x] = s[0];
}
__global__ void scan2(int* __restrict__ partial, int* __restrict__ offs)
{
    if (threadIdx.x == 0 && blockIdx.x == 0) {
        int run = 0;
        for (int i = 0; i < NBLKT; i++) { int v = partial[i]; partial[i] = run; run += v; }
        offs[N_NODES] = run;
    }
}
__global__ void scan3(const int* __restrict__ counts4, const int* __restrict__ partial,
                      int* __restrict__ offs)
{
    __shared__ int s[256];
    int i = blockIdx.x * 256 + threadIdx.x;
    int v = (i < N_NODES) ? cnt_tgt(counts4, i) : 0;
    s[threadIdx.x] = v;
    __syncthreads();
    for (int off = 1; off < 256; off <<= 1) {
        int add = (threadIdx.x >= off) ? s[threadIdx.x - off] : 0;
        __syncthreads();
        s[threadIdx.x] += add;
        __syncthreads();
    }
    if (i < N_NODES) offs[i] = partial[blockIdx.x] + s[threadIdx.x] - v;
}
__global__ void fill_kernel(const int* __restrict__ edges, const int* __restrict__ offs,
                            int* __restrict__ cursors, int* __restrict__ srcs)
{
    int e = blockIdx.x * 256 + threadIdx.x;
    if (e >= N_EDGES) return;
    int t = edges[e * 3];
    int s = edges[e * 3 + 1];
    int tg = edges[e * 3 + 2];
    int p = atomicAdd(&cursors[tg], 1);
    srcs[offs[tg] + p] = s | (t << 17);
}

// ---- gather: deep-MLP batching (8 row-loads in flight per wave) ----
__global__ __launch_bounds__(256) void gather_kernel(
    const int* __restrict__ offs, const int* __restrict__ srcs,
    const short* __restrict__ h, short* __restrict__ gath4, int c0, int nr)
{
    int w = (blockIdx.x * 256 + threadIdx.x) >> 6;
    int lane = threadIdx.x & 63;
    if (w >= nr) return;
    int tgt = c0 + w;
    int col = lane * 4;
    int e0 = offs[tgt], e1 = offs[tgt + 1];
    float4 a0 = make_float4(0.f,0.f,0.f,0.f), a1 = a0, a2 = a0, a3 = a0;

    #define ACCUM(V, PK) do {                                                  \
        float4 vv = make_float4(bf2f((unsigned short)((PK).x & 0xFFFF)),       \
                                bf2f((unsigned short)((PK).x >> 16)),          \
                                bf2f((unsigned short)((PK).y & 0xFFFF)),       \
                                bf2f((unsigned short)((PK).y >> 16)));         \
        int tt = (V) >> 17;                                                    \
        switch (tt) {                                                          \
        case 0: a0.x += vv.x; a0.y += vv.y; a0.z += vv.z; a0.w += vv.w; break; \
        case 1: a1.x += vv.x; a1.y += vv.y; a1.z += vv.z; a1.w += vv.w; break; \
        case 2: a2.x += vv.x; a2.y += vv.y; a2.z += vv.z; a2.w += vv.w; break; \
        default: a3.x += vv.x; a3.y += vv.y; a3.z += vv.z; a3.w += vv.w; }     \
    } while (0)

    int e = e0;
    for (; e + 8 <= e1; e += 8) {
        int v[8];
        #pragma unroll
        for (int i = 0; i < 8; i++)
            v[i] = __builtin_amdgcn_readfirstlane(srcs[e + i]);
        uint2 p[8];
        #pragma unroll
        for (int i = 0; i < 8; i++)
            p[i] = *(const uint2*)(h + (size_t)(v[i] & 0x1FFFF) * H + col);
        #pragma unroll
        for (int i = 0; i < 8; i++)
            ACCUM(v[i], p[i]);
    }
    if (e + 4 <= e1) {
        int v[4];
        #pragma unroll
        for (int i = 0; i < 4; i++)
            v[i] = __builtin_amdgcn_readfirstlane(srcs[e + i]);
        uint2 p[4];
        #pragma unroll
        for (int i = 0; i < 4; i++)
            p[i] = *(const uint2*)(h + (size_t)(v[i] & 0x1FFFF) * H + col);
        #pragma unroll
        for (int i = 0; i < 4; i++)
            ACCUM(v[i], p[i]);
        e += 4;
    }
    for (; e < e1; e++) {
        int v0 = __builtin_amdgcn_readfirstlane(srcs[e]);
        uint2 p0 = *(const uint2*)(h + (size_t)(v0 & 0x1FFFF) * H + col);
        ACCUM(v0, p0);
    }
    #undef ACCUM

    short* dst = gath4 + (size_t)w * 1024 + col;
    #define PACK(A) make_uint2( \
        ((unsigned)(unsigned short)f2bf((A).x)) | (((unsigned)(unsigned short)f2bf((A).y)) << 16), \
        ((unsigned)(unsigned short)f2bf((A).z)) | (((unsigned)(unsigned short)f2bf((A).w)) << 16))
    *(uint2*)(dst)       = PACK(a0);
    *(uint2*)(dst + 256) = PACK(a1);
    *(uint2*)(dst + 512) = PACK(a2);
    *(uint2*)(dst + 768) = PACK(a3);
    #undef PACK
}

// ---- mm1: bf16 MFMA matmul, async dbuf, one barrier/tile, XCD-aware swizzle ----
// grid must be (8, nNb*mpx) where nNb = 1<<nbShift N-blocks, mpx = ceil(nMb/8).
__global__ __launch_bounds__(256, 4) void mm_bf16(
    const short* __restrict__ A0, int s0, const short* __restrict__ A1, int s1, int K0,
    const short* __restrict__ BT, int Ktot,
    const float* __restrict__ bias,
    const int* __restrict__ cnt, int c0,
    short* __restrict__ C, int ldc, int nrows, int nbShift)
{
    __shared__ short As[2][128 * 32];
    __shared__ short Bs[2][128 * 32];
    const int tid = threadIdx.x;
    const int nMb = (nrows + 127) >> 7;
    const int mpx = (nMb + 7) >> 3;
    const int lin = blockIdx.x + blockIdx.y * 8;
    const int xcd = lin & 7;
    const int idx = lin >> 3;
    const int bmi = xcd * mpx + (idx >> nbShift);
    if (bmi >= nMb) return;
    const int bm = bmi << 7;
    const int bn = (idx & ((1 << nbShift) - 1)) << 7;
    const int lane = tid & 63;
    const int wave = tid >> 6;
    const int wm = (wave >> 1) * 64;
    const int wn = (wave & 1) * 64;
    const int q = lane >> 4;
    const int r16 = lane & 15;

    f32x4 acc[4][4];
    #pragma unroll
    for (int i = 0; i < 4; i++)
        #pragma unroll
        for (int j = 0; j < 4; j++)
            acc[i][j] = (f32x4){0.f, 0.f, 0.f, 0.f};

    const int seg0 = wave * 2;
    const int rloc0 = seg0 * 16 + (lane >> 2);
    const int rloc1 = rloc0 + 16;
    const int un = (lane & 3) * 8;
    int ga0 = bm + rloc0; if (ga0 >= nrows) ga0 = nrows - 1;
    int ga1 = bm + rloc1; if (ga1 >= nrows) ga1 = nrows - 1;

    const short* b0p = BT + (size_t)(bn + rloc0) * Ktot + un;
    const short* b1p = BT + (size_t)(bn + rloc1) * Ktot + un;
    const short* a0p = A0 + (size_t)ga0 * s0 + un;
    const short* a1p = A0 + (size_t)ga1 * s0 + un;
    const int nT = Ktot >> 5;

    async16(&As[0][seg0 * 512], a0p);
    async16(&As[0][(seg0 + 1) * 512], a1p);
    async16(&Bs[0][seg0 * 512], b0p);
    async16(&Bs[0][(seg0 + 1) * 512], b1p);
    a0p += 32; a1p += 32; b0p += 32; b1p += 32;

    int buf = 0;
    for (int i = 0; i < nT; i++) {
        __syncthreads();
        if (i + 1 < nT) {
            int nb = buf ^ 1;
            async16(&As[nb][seg0 * 512], a0p);
            async16(&As[nb][(seg0 + 1) * 512], a1p);
            async16(&Bs[nb][seg0 * 512], b0p);
            async16(&Bs[nb][(seg0 + 1) * 512], b1p);
            a0p += 32; a1p += 32; b0p += 32; b1p += 32;
        }
        bf16x8 af[4], bfr[4];
        #pragma unroll
        for (int mt = 0; mt < 4; mt++)
            af[mt] = *(const bf16x8*)&As[buf][(wm + mt * 16 + r16) * 32 + q * 8];
        #pragma unroll
        for (int nt = 0; nt < 4; nt++)
            bfr[nt] = *(const bf16x8*)&Bs[buf][(wn + nt * 16 + r16) * 32 + q * 8];
        #pragma unroll
        for (int mt = 0; mt < 4; mt++)
            #pragma unroll
            for (int nt = 0; nt < 4; nt++)
                acc[mt][nt] = __builtin_amdgcn_mfma_f32_16x16x32_bf16(af[mt], bfr[nt], acc[mt][nt], 0, 0, 0);
        buf ^= 1;
    }

    #pragma unroll
    for (int mt = 0; mt < 4; mt++) {
        #pragma unroll
        for (int reg = 0; reg < 4; reg++) {
            int row = bm + wm + mt * 16 + q * 4 + reg;
            if (row >= nrows) continue;
            #pragma unroll
            for (int nt = 0; nt < 4; nt++) {
                int col = bn + wn + nt * 16 + r16;
                float v = acc[mt][nt][reg];
                if (cnt) {
                    #pragma unroll
                    for (int t = 0; t < 4; t++)
                        v += (float)cnt[t * N_NODES + c0 + row] * bias[t * 256 + col];
                } else {
                    v += bias[col];
                }
                C[(size_t)row * ldc + col] = f2bf(v);
            }
        }
    }
}

// ---- mm2 fused: S-matmul + GRU epilogue, async dbuf, XCD-aware swizzle ----
// grid (8, 8*mpx); N fixed at 1024 (8 N-blocks).
__global__ __launch_bounds__(256, 4) void mm_gru(
    const short* __restrict__ A0, const short* __restrict__ A1,
    const short* __restrict__ BT,
    const float* __restrict__ bias,
    const short* __restrict__ hOld, short* __restrict__ hNew,
    int c0, int nrows)
{
    __shared__ short As[2][128 * 32];
    __shared__ short Bs[2][128 * 32];
    const int tid = threadIdx.x;
    const int nMb = (nrows + 127) >> 7;
    const int mpx = (nMb + 7) >> 3;
    const int lin = blockIdx.x + blockIdx.y * 8;
    const int xcd = lin & 7;
    const int idx = lin >> 3;
    const int bmi = xcd * mpx + (idx >> 3);
    if (bmi >= nMb) return;
    const int bm = bmi << 7;
    const int bn = (idx & 7) << 7;
    const int lane = tid & 63;
    const int wave = tid >> 6;
    const int wm = (wave >> 1) * 64;
    const int wn = (wave & 1) * 64;
    const int q = lane >> 4;
    const int r16 = lane & 15;
    const int Ktot = 512;

    f32x4 acc[4][4];
    #pragma unroll
    for (int i = 0; i < 4; i++)
        #pragma unroll
        for (int j = 0; j < 4; j++)
            acc[i][j] = (f32x4){0.f, 0.f, 0.f, 0.f};

    const int seg0 = wave * 2;
    const int rloc0 = seg0 * 16 + (lane >> 2);
    const int rloc1 = rloc0 + 16;
    const int un = (lane & 3) * 8;
    int ga0 = bm + rloc0; if (ga0 >= nrows) ga0 = nrows - 1;
    int ga1 = bm + rloc1; if (ga1 >= nrows) ga1 = nrows - 1;

    const short* b0p = BT + (size_t)(bn + rloc0) * Ktot + un;
    const short* b1p = BT + (size_t)(bn + rloc1) * Ktot + un;
    const short* a0p = A0 + (size_t)ga0 * 256 + un;
    const short* a1p = A0 + (size_t)ga1 * 256 + un;

    async16(&As[0][seg0 * 512], a0p);
    async16(&As[0][(seg0 + 1) * 512], a1p);
    async16(&Bs[0][seg0 * 512], b0p);
    async16(&Bs[0][(seg0 + 1) * 512], b1p);
    a0p += 32; a1p += 32; b0p += 32; b1p += 32;

    int buf = 0;
    for (int i = 0; i < 16; i++) {
        __syncthreads();
        if (i + 1 < 16) {
            int nb = buf ^ 1;
            async16(&As[nb][seg0 * 512], a0p);
            async16(&As[nb][(seg0 + 1) * 512], a1p);
            async16(&Bs[nb][seg0 * 512], b0p);
            async16(&Bs[nb][(seg0 + 1) * 512], b1p);
            if (i + 2 == 8) {
                a0p = A1 + (size_t)ga0 * 256 + un;
                a1p = A1 + (size_t)ga1 * 256 + un;
            } else {
                a0p += 32; a1p += 32;
            }
            b0p += 32; b1p += 32;
        }
        bf16x8 af[4], bfr[4];
        #pragma unroll
        for (int mt = 0; mt < 4; mt++)
            af[mt] = *(const bf16x8*)&As[buf][(wm + mt * 16 + r16) * 32 + q * 8];
        #pragma unroll
        for (int nt = 0; nt < 4; nt++)
            bfr[nt] = *(const bf16x8*)&Bs[buf][(wn + nt * 16 + r16) * 32 + q * 8];
        #pragma unroll
        for (int mt = 0; mt < 4; mt++)
            #pragma unroll
            for (int nt = 0; nt < 4; nt++)
                acc[mt][nt] = __builtin_amdgcn_mfma_f32_16x16x32_bf16(af[mt], bfr[nt], acc[mt][nt], 0, 0, 0);
        buf ^= 1;
    }

    // GRU epilogue (fast transcendentals)
    const int f = ((bn + wn) >> 2) + r16;
    const float bz = bias[bn + wn + 0 * 16 + r16];
    const float br_ = bias[bn + wn + 1 * 16 + r16];
    const float bx = bias[bn + wn + 2 * 16 + r16];
    const float bh = bias[bn + wn + 3 * 16 + r16];
    #pragma unroll
    for (int mt = 0; mt < 4; mt++) {
        #pragma unroll
        for (int reg = 0; reg < 4; reg++) {
            int row = bm + wm + mt * 16 + q * 4 + reg;
            if (row >= nrows) continue;
            float vz = acc[mt][0][reg] + bz;
            float vr = acc[mt][1][reg] + br_;
            float vx = acc[mt][2][reg] + bx;
            float vh = acc[mt][3][reg] + bh;
            size_t idx2 = (size_t)(c0 + row) * H + f;
            float hv = bf2f((unsigned short)hOld[idx2]);
            float z = fsigm(vz);
            float r = fsigm(vr);
            float cand = ftanh(vx + r * vh);
            hNew[idx2] = f2bf(z * hv + (1.0f - z) * cand);
        }
    }
}

// ---------------- gate logits ----------------
__global__ __launch_bounds__(256) void gate_kernel(const short* __restrict__ h,
                                                   const float* __restrict__ gW,
                                                   const float* __restrict__ gb,
                                                   float* __restrict__ g)
{
    int tid = blockIdx.x * 256 + threadIdx.x;
    int n = tid >> 6;
    if (n >= N_NODES) return;
    int lane = tid & 63;
    uint2 pk = *(const uint2*)(h + (size_t)n * H + lane * 4);
    float4 w = *(const float4*)(gW + lane * 4);
    float s = bf2f((unsigned short)(pk.x & 0xFFFF)) * w.x
            + bf2f((unsigned short)(pk.x >> 16))    * w.y
            + bf2f((unsigned short)(pk.y & 0xFFFF)) * w.z
            + bf2f((unsigned short)(pk.y >> 16))    * w.w;
    #pragma unroll
    for (int off = 32; off > 0; off >>= 1)
        s += __shfl_down(s, off);
    if (lane == 0) g[n] = s + gb[0];
}

// ---------------- readout phase A: per-graph max & sumexp ----------------
__global__ __launch_bounds__(256) void outA_kernel(const float* __restrict__ g,
                                                   const int* __restrict__ sizes,
                                                   float* __restrict__ gm,
                                                   float* __restrict__ gs)
{
    __shared__ float red[256];
    int gid = blockIdx.x;
    int tid = threadIdx.x;
    int start = 0, end = 0;
    {
        int c = 0;
        for (int i = 0; i < N_GRAPHS; i++) {
            int sz = sizes[i];
            if (i == gid) { start = c; end = c + sz; }
            c += sz;
        }
    }
    float m = -INFINITY;
    for (int n = start + tid; n < end; n += 256) m = fmaxf(m, g[n]);
    red[tid] = m; __syncthreads();
    for (int s = 128; s > 0; s >>= 1) {
        if (tid < s) red[tid] = fmaxf(red[tid], red[tid + s]);
        __syncthreads();
    }
    m = red[0]; __syncthreads();
    float s_ = 0.0f;
    for (int n = start + tid; n < end; n += 256) s_ += __expf(g[n] - m);
    red[tid] = s_; __syncthreads();
    for (int s = 128; s > 0; s >>= 1) {
        if (tid < s) red[tid] += red[tid + s];
        __syncthreads();
    }
    if (tid == 0) { gm[gid] = m; gs[gid] = red[0]; }
}

// ---------------- readout phase B: sliced e-weighted feature sums ----------------
__global__ __launch_bounds__(256) void outB_kernel(const short* __restrict__ h,
                                                   const float* __restrict__ g,
                                                   const int* __restrict__ sizes,
                                                   const float* __restrict__ gm,
                                                   float* __restrict__ accb)
{
    __shared__ float red4[4][256];
    int gid = blockIdx.x / OSLICE;
    int si = blockIdx.x % OSLICE;
    int tid = threadIdx.x;
    int wave = tid >> 6;
    int lane = tid & 63;
    int start = 0, end = 0;
    {
        int c = 0;
        for (int i = 0; i < N_GRAPHS; i++) {
            int sz = sizes[i];
            if (i == gid) { start = c; end = c + sz; }
            c += sz;
        }
    }
    float m = gm[gid];
    float a0 = 0.f, a1 = 0.f, a2 = 0.f, a3 = 0.f;
    for (int n = start + si * 4 + wave; n < end; n += OSLICE * 4) {
        float e = __expf(g[n] - m);
        uint2 pk = *(const uint2*)(h + (size_t)n * H + lane * 4);
        a0 += e * bf2f((unsigned short)(pk.x & 0xFFFF));
        a1 += e * bf2f((unsigned short)(pk.x >> 16));
        a2 += e * bf2f((unsigned short)(pk.y & 0xFFFF));
        a3 += e * bf2f((unsigned short)(pk.y >> 16));
    }
    red4[wave][lane * 4 + 0] = a0;
    red4[wave][lane * 4 + 1] = a1;
    red4[wave][lane * 4 + 2] = a2;
    red4[wave][lane * 4 + 3] = a3;
    __syncthreads();
    float acc = red4[0][tid] + red4[1][tid] + red4[2][tid] + red4[3][tid];
    unsafeAtomicAdd(&accb[(size_t)gid * 256 + tid], acc);
}

// ---------------- readout phase C: project to outputs ----------------
__global__ __launch_bounds__(256) void outC_kernel(const float* __restrict__ accb,
                                                   const float* __restrict__ gs,
                                                   const float* __restrict__ outW,
                                                   const float* __restrict__ outBs,
                                                   float* __restrict__ out)
{
    __shared__ float red[256];
    int gid = blockIdx.x;
    int tid = threadIdx.x;
    float ssum = gs[gid];
    float inv = 1.0f / (ssum + 1e-16f);
    float a = accb[(size_t)gid * 256 + tid];
    for (int c = 0; c < 2; c++) {
        red[tid] = a * outW[tid * 2 + c];
        __syncthreads();
        for (int s = 128; s > 0; s >>= 1) {
            if (tid < s) red[tid] += red[tid + s];
            __syncthreads();
        }
        if (tid == 0) out[gid * 2 + c] = red[0] * inv + outBs[c] * (ssum * inv);
        __syncthreads();
    }
}

static inline size_t alup(size_t x) { return (x + 255) & ~(size_t)255; }

extern "C" void kernel_launch(void* const* d_in, const int* in_sizes, int n_in,
                              void* d_out, int out_size, void* d_ws, size_t ws_size,
                              hipStream_t stream)
{
    const int*   nodes  = (const int*)d_in[0];
    const int*   gsizes = (const int*)d_in[1];
    const int*   edges  = (const int*)d_in[2];
    const float* embed  = (const float*)d_in[3];
    const float* type_w = (const float*)d_in[4];
    const float* type_b = (const float*)d_in[5];
    const float* gru_W  = (const float*)d_in[6];
    const float* gru_U  = (const float*)d_in[7];
    const float* gru_bi = (const float*)d_in[8];
    const float* gru_br = (const float*)d_in[9];
    const float* gate_W = (const float*)d_in[10];
    const float* gate_b = (const float*)d_in[11];
    const float* out_W  = (const float*)d_in[12];
    const float* out_b  = (const float*)d_in[13];
    float* out = (float*)d_out;

    const int CHMAX = 33334;
    const int c0s[3] = {0, 33334, 66667};
    const int nrs[3] = {33334, 33333, 33333};

    // ---- workspace layout (bytes), total ~199 MB ----
    const size_t SZ_HB   = alup((size_t)N_NODES * H * 2);
    const size_t SZ_SCR1 = alup((size_t)CHMAX * 1024 * 2);
    const size_t SZ_SCR2 = alup((size_t)CHMAX * 256 * 2);
    const size_t SZ_G    = alup((size_t)N_NODES * 4);
    const size_t SZ_PE   = alup((size_t)(L_POS + 1) * H * 4);
    const size_t SZ_WST  = alup((size_t)2 * 256 * 1024 * 2);
    const size_t SZ_BC   = alup((size_t)2 * 1024 * 512 * 2);
    const size_t SZ_BIAS = alup((size_t)2 * 1024 * 4);
    const size_t SZ_CNT4 = alup((size_t)NBUCK4 * 4);
    const size_t SZ_CUR  = alup((size_t)N_NODES * 4);
    const size_t SZ_ACC  = alup((size_t)N_GRAPHS * 256 * 4);
    const size_t SZ_OFF  = alup((size_t)(N_NODES + 1) * 4);
    const size_t SZ_SRC  = alup((size_t)N_EDGES * 4);
    const size_t SZ_PART = alup((size_t)NBLKT * 4);
    const size_t SZ_GMS  = alup((size_t)N_GRAPHS * 4);
    size_t need = 2 * SZ_HB + SZ_SCR1 + SZ_SCR2 + SZ_G + SZ_PE + SZ_WST + SZ_BC + SZ_BIAS +
                  SZ_CNT4 + SZ_CUR + SZ_ACC + SZ_OFF + SZ_SRC + SZ_PART + 2 * SZ_GMS;
    if (ws_size < need) return;

    char* base = (char*)d_ws;
    short* hA     = (short*)base;  base += SZ_HB;
    short* hB     = (short*)base;  base += SZ_HB;
    short* scr1   = (short*)base;  base += SZ_SCR1;
    short* scr2   = (short*)base;  base += SZ_SCR2;
    float* g      = (float*)base;  base += SZ_G;
    float* peTab  = (float*)base;  base += SZ_PE;
    short* Wstack = (short*)base;  base += SZ_WST;
    short* Bcomb  = (short*)base;  base += SZ_BC;
    float* biasC  = (float*)base;  base += SZ_BIAS;
    int*   counts4= (int*)base;    base += SZ_CNT4;
    int*   cursors= (int*)base;    base += SZ_CUR;
    float* accb   = (float*)base;  base += SZ_ACC;
    int*   offs   = (int*)base;    base += SZ_OFF;
    int*   srcs   = (int*)base;    base += SZ_SRC;
    int*   partial= (int*)base;    base += SZ_PART;
    float* gm     = (float*)base;  base += SZ_GMS;
    float* gs     = (float*)base;  base += SZ_GMS;

    // ---- prep ----
    pe_kernel<<<L_POS + 1, 256, 0, stream>>>(peTab);
    cvt_wstack<<<(2 * 256 * 1024) / 256, 256, 0, stream>>>(type_w, Wstack);
    cvt_comb<<<(2 * 1024 * 512) / 256, 256, 0, stream>>>(gru_W, gru_U, Bcomb);
    cvt_bias<<<8, 256, 0, stream>>>(gru_bi, gru_br, biasC);
    {   // zero counts4 + cursors + accb (contiguous)
        int n4 = (int)((SZ_CNT4 + SZ_CUR + SZ_ACC) / 16);
        zero_int<<<(n4 + 255) / 256, 256, 0, stream>>>((int4*)counts4, n4);
    }
    histo_kernel<<<(N_EDGES + 255) / 256, 256, 0, stream>>>(edges, counts4);
    scan1<<<NBLKT, 256, 0, stream>>>(counts4, partial);
    scan2<<<1, 64, 0, stream>>>(partial, offs);
    scan3<<<NBLKT, 256, 0, stream>>>(counts4, partial, offs);
    fill_kernel<<<(N_EDGES + 255) / 256, 256, 0, stream>>>(edges, offs, cursors, srcs);
    init_h_kernel<<<N_NODES, H, 0, stream>>>(nodes, embed, peTab, hA);

    short* cur = hA;
    short* nxt = hB;
    const int steps[2] = {3, 1};
    for (int l = 0; l < 2; l++) {
        const short* WS = Wstack + (size_t)l * 256 * 1024;
        const float* Tb = type_b + (size_t)l * 4 * 256;
        const short* BC = Bcomb + (size_t)l * 1024 * 512;
        const float* Cb = biasC + (size_t)l * 1024;
        for (int s = 0; s < steps[l]; s++) {
            for (int c = 0; c < 3; c++) {
                int c0 = c0s[c], nr = nrs[c];
                int nMb = (nr + 127) / 128;
                int mpx = (nMb + 7) / 8;
                gather_kernel<<<(nr * 64 + 255) / 256, 256, 0, stream>>>(offs, srcs, cur, scr1, c0, nr);
                dim3 g1(8, 2 * mpx);   // nNb=2 (nbShift=1)
                mm_bf16<<<g1, 256, 0, stream>>>(scr1, 1024, nullptr, 0, 1024,
                                                WS, 1024, Tb, counts4, c0,
                                                scr2, 256, nr, 1);
                dim3 g2(8, 8 * mpx);   // nNb=8
                mm_gru<<<g2, 256, 0, stream>>>(scr2, cur + (size_t)c0 * H,
                                               BC, Cb, cur, nxt, c0, nr);
            }
            short* t = cur; cur = nxt; nxt = t;
        }
    }

    gate_kernel<<<(N_NODES * 64) / 256, 256, 0, stream>>>(cur, gate_W, gate_b, g);
    outA_kernel<<<N_GRAPHS, 256, 0, stream>>>(g, gsizes, gm, gs);
    outB_kernel<<<N_GRAPHS * OSLICE, 256, 0, stream>>>(cur, g, gsizes, gm, accb);
    outC_kernel<<<N_GRAPHS, 256, 0, stream>>>(accb, gs, out_W, out_b, out);
}

// Round 24
// 1795.892 us; speedup vs baseline: 1.4157x; 1.0762x over previous
//
#include <hip/hip_runtime.h>
#include <math.h>

#define N_NODES 100000
#define N_GRAPHS 100
#define N_EDGES 1000000
#define H 256
#define L_POS 512
#define NBUCK4 (4 * N_NODES)
#define NBLKT ((N_NODES + 255) / 256)
#define OSLICE 8

typedef short bf16x8 __attribute__((ext_vector_type(8)));
typedef float f32x4  __attribute__((ext_vector_type(4)));

__device__ inline short f2bf(float f) {
    union { float f; unsigned u; } v; v.f = f;
    unsigned r = (v.u + 0x7FFF + ((v.u >> 16) & 1)) >> 16;
    return (short)r;
}
__device__ inline float bf2f(unsigned short u) {
    union { unsigned u; float f; } v; v.u = ((unsigned)u) << 16;
    return v.f;
}

// fast transcendentals (hw v_exp_f32 path)
__device__ inline float fsigm(float x) { return 1.0f / (1.0f + __expf(-x)); }
__device__ inline float ftanh(float x) {
    float t = __expf(-2.0f * fabsf(x));
    float y = 1.0f - 2.0f * t / (1.0f + t);
    return copysignf(y, x);
}

// async global->LDS, 16B per lane; lds dest = wave-uniform base + lane*16
__device__ inline void async16(short* l, const short* g) {
    __builtin_amdgcn_global_load_lds(
        (const __attribute__((address_space(1))) void*)g,
        (__attribute__((address_space(3))) void*)l, 16, 0, 0);
}

// ---------------- zero ints ----------------
__global__ void zero_int(int4* __restrict__ p, int n4)
{
    int i = blockIdx.x * 256 + threadIdx.x;
    if (i < n4) p[i] = make_int4(0, 0, 0, 0);
}

// ---------------- PE table ----------------
__global__ void pe_kernel(float* __restrict__ pe)
{
    int p = blockIdx.x;
    int j = threadIdx.x;
    float v = 0.0f;
    if (p > 0) {
        float pos = (float)(p - 1);
        float denom = powf(10000.0f, 2.0f * (float)j / (float)H);
        float ang = pos / denom;
        v = (j & 1) ? cosf(ang) : sinf(ang);
    }
    pe[p * H + j] = v;
}

// ---------------- init h (bf16) ----------------
__global__ void init_h_kernel(const int* __restrict__ nodes,
                              const float* __restrict__ embed,
                              const float* __restrict__ pe,
                              short* __restrict__ h)
{
    int n = blockIdx.x;
    int j = threadIdx.x;
    int tok = nodes[n];
    int p = nodes[N_NODES + n];
    if (p > L_POS) p = L_POS;
    h[(size_t)n * H + j] = f2bf(embed[(size_t)tok * H + j] + pe[p * H + j]);
}

// ---------------- weight prep ----------------
__global__ void cvt_wstack(const float* __restrict__ w, short* __restrict__ wt)
{
    int idx = blockIdx.x * 256 + threadIdx.x;
    if (idx >= 2 * 256 * 1024) return;
    int l = idx / (256 * 1024);
    int rem = idx % (256 * 1024);
    int n = rem >> 10, k = rem & 1023;
    int t = k >> 8, kk = k & 255;
    wt[idx] = f2bf(w[(((size_t)(l * 4 + t)) * 256 + kk) * 256 + n]);
}
// permuted column for GRU-fused epilogue: gate g, feature f -> p
__host__ __device__ inline int permcol(int g, int f)
{
    return ((f >> 4) << 6) + (g << 4) + (f & 15);
}
__global__ void cvt_comb(const float* __restrict__ W, const float* __restrict__ U,
                         short* __restrict__ B)
{
    int idx = blockIdx.x * 256 + threadIdx.x;
    if (idx >= 2 * 1024 * 512) return;
    int l = idx / (1024 * 512);
    int rem = idx % (1024 * 512);
    int n = rem >> 9, k = rem & 511;
    float v = 0.0f;
    if (n < 512) {
        v = (k < 256) ? W[((size_t)l * 256 + k) * 768 + n]
                      : U[((size_t)l * 256 + (k - 256)) * 768 + n];
    } else if (n < 768) {
        if (k < 256) v = W[((size_t)l * 256 + k) * 768 + n];
    } else {
        if (k >= 256) v = U[((size_t)l * 256 + (k - 256)) * 768 + (n - 256)];
    }
    int g = n >> 8, f = n & 255;
    B[((size_t)l * 1024 + permcol(g, f)) * 512 + k] = f2bf(v);
}
__global__ void cvt_bias(const float* __restrict__ bi, const float* __restrict__ br,
                         float* __restrict__ biasC)
{
    int idx = blockIdx.x * 256 + threadIdx.x;
    if (idx >= 2048) return;
    int l = idx >> 10, n = idx & 1023;
    float v;
    if (n < 512)      v = bi[l * 768 + n] + br[l * 768 + n];
    else if (n < 768) v = bi[l * 768 + n];
    else              v = br[l * 768 + (n - 256)];
    int g = n >> 8, f = n & 255;
    biasC[(size_t)l * 1024 + permcol(g, f)] = v;
}

// ---------------- CSR build ----------------
__global__ void histo_kernel(const int* __restrict__ edges, int* __restrict__ counts4)
{
    int e = blockIdx.x * 256 + threadIdx.x;
    if (e >= N_EDGES) return;
    int t = edges[e * 3];
    int tg = edges[e * 3 + 2];
    atomicAdd(&counts4[t * N_NODES + tg], 1);
}
__device__ inline int cnt_tgt(const int* counts4, int i)
{
    return counts4[i] + counts4[N_NODES + i] + counts4[2 * N_NODES + i] + counts4[3 * N_NODES + i];
}
__global__ void scan1(const int* __restrict__ counts4, int* __restrict__ partial)
{
    __shared__ int s[256];
    int i = blockIdx.x * 256 + threadIdx.x;
    s[threadIdx.x] = (i < N_NODES) ? cnt_tgt(counts4, i) : 0;
    __syncthreads();
    for (int off = 128; off > 0; off >>= 1) {
        if (threadIdx.x < off) s[threadIdx.x] += s[threadIdx.x + off];
        __syncthreads();
    }
    if (threadIdx.x == 0) partial[blockIdx.x] = s[0];
}
__global__ void scan2(int* __restrict__ partial, int* __restrict__ offs)
{
    if (threadIdx.x == 0 && blockIdx.x == 0) {
        int run = 0;
        for (int i = 0; i < NBLKT; i++) { int v = partial[i]; partial[i] = run; run += v; }
        offs[N_NODES] = run;
    }
}
__global__ void scan3(const int* __restrict__ counts4, const int* __restrict__ partial,
                      int* __restrict__ offs)
{
    __shared__ int s[256];
    int i = blockIdx.x * 256 + threadIdx.x;
    int v = (i < N_NODES) ? cnt_tgt(counts4, i) : 0;
    s[threadIdx.x] = v;
    __syncthreads();
    for (int off = 1; off < 256; off <<= 1) {
        int add = (threadIdx.x >= off) ? s[threadIdx.x - off] : 0;
        __syncthreads();
        s[threadIdx.x] += add;
        __syncthreads();
    }
    if (i < N_NODES) offs[i] = partial[blockIdx.x] + s[threadIdx.x] - v;
}
__global__ void fill_kernel(const int* __restrict__ edges, const int* __restrict__ offs,
                            int* __restrict__ cursors, int* __restrict__ srcs)
{
    int e = blockIdx.x * 256 + threadIdx.x;
    if (e >= N_EDGES) return;
    int t = edges[e * 3];
    int s = edges[e * 3 + 1];
    int tg = edges[e * 3 + 2];
    int p = atomicAdd(&cursors[tg], 1);
    srcs[offs[tg] + p] = s | (t << 17);
}

// ---- gather: deep-MLP batching (8 row-loads in flight per wave) ----
__global__ __launch_bounds__(256) void gather_kernel(
    const int* __restrict__ offs, const int* __restrict__ srcs,
    const short* __restrict__ h, short* __restrict__ gath4, int c0, int nr)
{
    int w = (blockIdx.x * 256 + threadIdx.x) >> 6;
    int lane = threadIdx.x & 63;
    if (w >= nr) return;
    int tgt = c0 + w;
    int col = lane * 4;
    int e0 = offs[tgt], e1 = offs[tgt + 1];
    float4 a0 = make_float4(0.f,0.f,0.f,0.f), a1 = a0, a2 = a0, a3 = a0;

    #define ACCUM(V, PK) do {                                                  \
        float4 vv = make_float4(bf2f((unsigned short)((PK).x & 0xFFFF)),       \
                                bf2f((unsigned short)((PK).x >> 16)),          \
                                bf2f((unsigned short)((PK).y & 0xFFFF)),       \
                                bf2f((unsigned short)((PK).y >> 16)));         \
        int tt = (V) >> 17;                                                    \
        switch (tt) {                                                          \
        case 0: a0.x += vv.x; a0.y += vv.y; a0.z += vv.z; a0.w += vv.w; break; \
        case 1: a1.x += vv.x; a1.y += vv.y; a1.z += vv.z; a1.w += vv.w; break; \
        case 2: a2.x += vv.x; a2.y += vv.y; a2.z += vv.z; a2.w += vv.w; break; \
        default: a3.x += vv.x; a3.y += vv.y; a3.z += vv.z; a3.w += vv.w; }     \
    } while (0)

    int e = e0;
    for (; e + 8 <= e1; e += 8) {
        int v[8];
        #pragma unroll
        for (int i = 0; i < 8; i++)
            v[i] = __builtin_amdgcn_readfirstlane(srcs[e + i]);
        uint2 p[8];
        #pragma unroll
        for (int i = 0; i < 8; i++)
            p[i] = *(const uint2*)(h + (size_t)(v[i] & 0x1FFFF) * H + col);
        #pragma unroll
        for (int i = 0; i < 8; i++)
            ACCUM(v[i], p[i]);
    }
    if (e + 4 <= e1) {
        int v[4];
        #pragma unroll
        for (int i = 0; i < 4; i++)
            v[i] = __builtin_amdgcn_readfirstlane(srcs[e + i]);
        uint2 p[4];
        #pragma unroll
        for (int i = 0; i < 4; i++)
            p[i] = *(const uint2*)(h + (size_t)(v[i] & 0x1FFFF) * H + col);
        #pragma unroll
        for (int i = 0; i < 4; i++)
            ACCUM(v[i], p[i]);
        e += 4;
    }
    for (; e < e1; e++) {
        int v0 = __builtin_amdgcn_readfirstlane(srcs[e]);
        uint2 p0 = *(const uint2*)(h + (size_t)(v0 & 0x1FFFF) * H + col);
        ACCUM(v0, p0);
    }
    #undef ACCUM

    short* dst = gath4 + (size_t)w * 1024 + col;
    #define PACK(A) make_uint2( \
        ((unsigned)(unsigned short)f2bf((A).x)) | (((unsigned)(unsigned short)f2bf((A).y)) << 16), \
        ((unsigned)(unsigned short)f2bf((A).z)) | (((unsigned)(unsigned short)f2bf((A).w)) << 16))
    *(uint2*)(dst)       = PACK(a0);
    *(uint2*)(dst + 256) = PACK(a1);
    *(uint2*)(dst + 512) = PACK(a2);
    *(uint2*)(dst + 768) = PACK(a3);
    #undef PACK
}

// ---- mm1: bf16 MFMA matmul, async dbuf, one barrier/tile, XCD-aware swizzle ----
// grid must be (8, nNb*mpx) where nNb = 1<<nbShift N-blocks, mpx = ceil(nMb/8).
__global__ __launch_bounds__(256, 4) void mm_bf16(
    const short* __restrict__ A0, int s0, const short* __restrict__ A1, int s1, int K0,
    const short* __restrict__ BT, int Ktot,
    const float* __restrict__ bias,
    const int* __restrict__ cnt, int c0,
    short* __restrict__ C, int ldc, int nrows, int nbShift)
{
    __shared__ short As[2][128 * 32];
    __shared__ short Bs[2][128 * 32];
    const int tid = threadIdx.x;
    const int nMb = (nrows + 127) >> 7;
    const int mpx = (nMb + 7) >> 3;
    const int lin = blockIdx.x + blockIdx.y * 8;
    const int xcd = lin & 7;
    const int idx = lin >> 3;
    const int bmi = xcd * mpx + (idx >> nbShift);
    if (bmi >= nMb) return;
    const int bm = bmi << 7;
    const int bn = (idx & ((1 << nbShift) - 1)) << 7;
    const int lane = tid & 63;
    const int wave = tid >> 6;
    const int wm = (wave >> 1) * 64;
    const int wn = (wave & 1) * 64;
    const int q = lane >> 4;
    const int r16 = lane & 15;

    f32x4 acc[4][4];
    #pragma unroll
    for (int i = 0; i < 4; i++)
        #pragma unroll
        for (int j = 0; j < 4; j++)
            acc[i][j] = (f32x4){0.f, 0.f, 0.f, 0.f};

    const int seg0 = wave * 2;
    const int rloc0 = seg0 * 16 + (lane >> 2);
    const int rloc1 = rloc0 + 16;
    const int un = (lane & 3) * 8;
    int ga0 = bm + rloc0; if (ga0 >= nrows) ga0 = nrows - 1;
    int ga1 = bm + rloc1; if (ga1 >= nrows) ga1 = nrows - 1;

    const short* b0p = BT + (size_t)(bn + rloc0) * Ktot + un;
    const short* b1p = BT + (size_t)(bn + rloc1) * Ktot + un;
    const short* a0p = A0 + (size_t)ga0 * s0 + un;
    const short* a1p = A0 + (size_t)ga1 * s0 + un;
    const int nT = Ktot >> 5;

    async16(&As[0][seg0 * 512], a0p);
    async16(&As[0][(seg0 + 1) * 512], a1p);
    async16(&Bs[0][seg0 * 512], b0p);
    async16(&Bs[0][(seg0 + 1) * 512], b1p);
    a0p += 32; a1p += 32; b0p += 32; b1p += 32;

    int buf = 0;
    for (int i = 0; i < nT; i++) {
        __syncthreads();
        if (i + 1 < nT) {
            int nb = buf ^ 1;
            async16(&As[nb][seg0 * 512], a0p);
            async16(&As[nb][(seg0 + 1) * 512], a1p);
            async16(&Bs[nb][seg0 * 512], b0p);
            async16(&Bs[nb][(seg0 + 1) * 512], b1p);
            a0p += 32; a1p += 32; b0p += 32; b1p += 32;
        }
        bf16x8 af[4], bfr[4];
        #pragma unroll
        for (int mt = 0; mt < 4; mt++)
            af[mt] = *(const bf16x8*)&As[buf][(wm + mt * 16 + r16) * 32 + q * 8];
        #pragma unroll
        for (int nt = 0; nt < 4; nt++)
            bfr[nt] = *(const bf16x8*)&Bs[buf][(wn + nt * 16 + r16) * 32 + q * 8];
        #pragma unroll
        for (int mt = 0; mt < 4; mt++)
            #pragma unroll
            for (int nt = 0; nt < 4; nt++)
                acc[mt][nt] = __builtin_amdgcn_mfma_f32_16x16x32_bf16(af[mt], bfr[nt], acc[mt][nt], 0, 0, 0);
        buf ^= 1;
    }

    #pragma unroll
    for (int mt = 0; mt < 4; mt++) {
        #pragma unroll
        for (int reg = 0; reg < 4; reg++) {
            int row = bm + wm + mt * 16 + q * 4 + reg;
            if (row >= nrows) continue;
            #pragma unroll
            for (int nt = 0; nt < 4; nt++) {
                int col = bn + wn + nt * 16 + r16;
                float v = acc[mt][nt][reg];
                if (cnt) {
                    #pragma unroll
                    for (int t = 0; t < 4; t++)
                        v += (float)cnt[t * N_NODES + c0 + row] * bias[t * 256 + col];
                } else {
                    v += bias[col];
                }
                C[(size_t)row * ldc + col] = f2bf(v);
            }
        }
    }
}

// ---- mm2 fused: S-matmul + GRU epilogue, async dbuf, XCD-aware swizzle ----
// grid (8, 8*mpx); N fixed at 1024 (8 N-blocks).
__global__ __launch_bounds__(256, 4) void mm_gru(
    const short* __restrict__ A0, const short* __restrict__ A1,
    const short* __restrict__ BT,
    const float* __restrict__ bias,
    const short* __restrict__ hOld, short* __restrict__ hNew,
    int c0, int nrows)
{
    __shared__ short As[2][128 * 32];
    __shared__ short Bs[2][128 * 32];
    const int tid = threadIdx.x;
    const int nMb = (nrows + 127) >> 7;
    const int mpx = (nMb + 7) >> 3;
    const int lin = blockIdx.x + blockIdx.y * 8;
    const int xcd = lin & 7;
    const int idx = lin >> 3;
    const int bmi = xcd * mpx + (idx >> 3);
    if (bmi >= nMb) return;
    const int bm = bmi << 7;
    const int bn = (idx & 7) << 7;
    const int lane = tid & 63;
    const int wave = tid >> 6;
    const int wm = (wave >> 1) * 64;
    const int wn = (wave & 1) * 64;
    const int q = lane >> 4;
    const int r16 = lane & 15;
    const int Ktot = 512;

    f32x4 acc[4][4];
    #pragma unroll
    for (int i = 0; i < 4; i++)
        #pragma unroll
        for (int j = 0; j < 4; j++)
            acc[i][j] = (f32x4){0.f, 0.f, 0.f, 0.f};

    const int seg0 = wave * 2;
    const int rloc0 = seg0 * 16 + (lane >> 2);
    const int rloc1 = rloc0 + 16;
    const int un = (lane & 3) * 8;
    int ga0 = bm + rloc0; if (ga0 >= nrows) ga0 = nrows - 1;
    int ga1 = bm + rloc1; if (ga1 >= nrows) ga1 = nrows - 1;

    const short* b0p = BT + (size_t)(bn + rloc0) * Ktot + un;
    const short* b1p = BT + (size_t)(bn + rloc1) * Ktot + un;
    const short* a0p = A0 + (size_t)ga0 * 256 + un;
    const short* a1p = A0 + (size_t)ga1 * 256 + un;

    async16(&As[0][seg0 * 512], a0p);
    async16(&As[0][(seg0 + 1) * 512], a1p);
    async16(&Bs[0][seg0 * 512], b0p);
    async16(&Bs[0][(seg0 + 1) * 512], b1p);
    a0p += 32; a1p += 32; b0p += 32; b1p += 32;

    int buf = 0;
    for (int i = 0; i < 16; i++) {
        __syncthreads();
        if (i + 1 < 16) {
            int nb = buf ^ 1;
            async16(&As[nb][seg0 * 512], a0p);
            async16(&As[nb][(seg0 + 1) * 512], a1p);
            async16(&Bs[nb][seg0 * 512], b0p);
            async16(&Bs[nb][(seg0 + 1) * 512], b1p);
            if (i + 2 == 8) {
                a0p = A1 + (size_t)ga0 * 256 + un;
                a1p = A1 + (size_t)ga1 * 256 + un;
            } else {
                a0p += 32; a1p += 32;
            }
            b0p += 32; b1p += 32;
        }
        bf16x8 af[4], bfr[4];
        #pragma unroll
        for (int mt = 0; mt < 4; mt++)
            af[mt] = *(const bf16x8*)&As[buf][(wm + mt * 16 + r16) * 32 + q * 8];
        #pragma unroll
        for (int nt = 0; nt < 4; nt++)
            bfr[nt] = *(const bf16x8*)&Bs[buf][(wn + nt * 16 + r16) * 32 + q * 8];
        #pragma unroll
        for (int mt = 0; mt < 4; mt++)
            #pragma unroll
            for (int nt = 0; nt < 4; nt++)
                acc[mt][nt] = __builtin_amdgcn_mfma_f32_16x16x32_bf16(af[mt], bfr[nt], acc[mt][nt], 0, 0, 0);
        buf ^= 1;
    }

    // GRU epilogue (fast transcendentals)
    const int f = ((bn + wn) >> 2) + r16;
    const float bz = bias[bn + wn + 0 * 16 + r16];
    const float br_ = bias[bn + wn + 1 * 16 + r16];
    const float bx = bias[bn + wn + 2 * 16 + r16];
    const float bh = bias[bn + wn + 3 * 16 + r16];
    #pragma unroll
    for (int mt = 0; mt < 4; mt++) {
        #pragma unroll
        for (int reg = 0; reg < 4; reg++) {
            int row = bm + wm + mt * 16 + q * 4 + reg;
            if (row >= nrows) continue;
            float vz = acc[mt][0][reg] + bz;
            float vr = acc[mt][1][reg] + br_;
            float vx = acc[mt][2][reg] + bx;
            float vh = acc[mt][3][reg] + bh;
            size_t idx2 = (size_t)(c0 + row) * H + f;
            float hv = bf2f((unsigned short)hOld[idx2]);
            float z = fsigm(vz);
            float r = fsigm(vr);
            float cand = ftanh(vx + r * vh);
            hNew[idx2] = f2bf(z * hv + (1.0f - z) * cand);
        }
    }
}

// ---------------- gate logits ----------------
__global__ __launch_bounds__(256) void gate_kernel(const short* __restrict__ h,
                                                   const float* __restrict__ gW,
                                                   const float* __restrict__ gb,
                                                   float* __restrict__ g)
{
    int tid = blockIdx.x * 256 + threadIdx.x;
    int n = tid >> 6;
    if (n >= N_NODES) return;
    int lane = tid & 63;
    uint2 pk = *(const uint2*)(h + (size_t)n * H + lane * 4);
    float4 w = *(const float4*)(gW + lane * 4);
    float s = bf2f((unsigned short)(pk.x & 0xFFFF)) * w.x
            + bf2f((unsigned short)(pk.x >> 16))    * w.y
            + bf2f((unsigned short)(pk.y & 0xFFFF)) * w.z
            + bf2f((unsigned short)(pk.y >> 16))    * w.w;
    #pragma unroll
    for (int off = 32; off > 0; off >>= 1)
        s += __shfl_down(s, off);
    if (lane == 0) g[n] = s + gb[0];
}

// ---------------- readout phase A: per-graph max & sumexp ----------------
__global__ __launch_bounds__(256) void outA_kernel(const float* __restrict__ g,
                                                   const int* __restrict__ sizes,
                                                   float* __restrict__ gm,
                                                   float* __restrict__ gs)
{
    __shared__ float red[256];
    int gid = blockIdx.x;
    int tid = threadIdx.x;
    int start = 0, end = 0;
    {
        int c = 0;
        for (int i = 0; i < N_GRAPHS; i++) {
            int sz = sizes[i];
            if (i == gid) { start = c; end = c + sz; }
            c += sz;
        }
    }
    float m = -INFINITY;
    for (int n = start + tid; n < end; n += 256) m = fmaxf(m, g[n]);
    red[tid] = m; __syncthreads();
    for (int s = 128; s > 0; s >>= 1) {
        if (tid < s) red[tid] = fmaxf(red[tid], red[tid + s]);
        __syncthreads();
    }
    m = red[0]; __syncthreads();
    float s_ = 0.0f;
    for (int n = start + tid; n < end; n += 256) s_ += __expf(g[n] - m);
    red[tid] = s_; __syncthreads();
    for (int s = 128; s > 0; s >>= 1) {
        if (tid < s) red[tid] += red[tid + s];
        __syncthreads();
    }
    if (tid == 0) { gm[gid] = m; gs[gid] = red[0]; }
}

// ---------------- readout phase B: sliced e-weighted feature sums ----------------
__global__ __launch_bounds__(256) void outB_kernel(const short* __restrict__ h,
                                                   const float* __restrict__ g,
                                                   const int* __restrict__ sizes,
                                                   const float* __restrict__ gm,
                                                   float* __restrict__ accb)
{
    __shared__ float red4[4][256];
    int gid = blockIdx.x / OSLICE;
    int si = blockIdx.x % OSLICE;
    int tid = threadIdx.x;
    int wave = tid >> 6;
    int lane = tid & 63;
    int start = 0, end = 0;
    {
        int c = 0;
        for (int i = 0; i < N_GRAPHS; i++) {
            int sz = sizes[i];
            if (i == gid) { start = c; end = c + sz; }
            c += sz;
        }
    }
    float m = gm[gid];
    float a0 = 0.f, a1 = 0.f, a2 = 0.f, a3 = 0.f;
    for (int n = start + si * 4 + wave; n < end; n += OSLICE * 4) {
        float e = __expf(g[n] - m);
        uint2 pk = *(const uint2*)(h + (size_t)n * H + lane * 4);
        a0 += e * bf2f((unsigned short)(pk.x & 0xFFFF));
        a1 += e * bf2f((unsigned short)(pk.x >> 16));
        a2 += e * bf2f((unsigned short)(pk.y & 0xFFFF));
        a3 += e * bf2f((unsigned short)(pk.y >> 16));
    }
    red4[wave][lane * 4 + 0] = a0;
    red4[wave][lane * 4 + 1] = a1;
    red4[wave][lane * 4 + 2] = a2;
    red4[wave][lane * 4 + 3] = a3;
    __syncthreads();
    float acc = red4[0][tid] + red4[1][tid] + red4[2][tid] + red4[3][tid];
    unsafeAtomicAdd(&accb[(size_t)gid * 256 + tid], acc);
}

// ---------------- readout phase C: project to outputs ----------------
__global__ __launch_bounds__(256) void outC_kernel(const float* __restrict__ accb,
                                                   const float* __restrict__ gs,
                                                   const float* __restrict__ outW,
                                                   const float* __restrict__ outBs,
                                                   float* __restrict__ out)
{
    __shared__ float red[256];
    int gid = blockIdx.x;
    int tid = threadIdx.x;
    float ssum = gs[gid];
    float inv = 1.0f / (ssum + 1e-16f);
    float a = accb[(size_t)gid * 256 + tid];
    for (int c = 0; c < 2; c++) {
        red[tid] = a * outW[tid * 2 + c];
        __syncthreads();
        for (int s = 128; s > 0; s >>= 1) {
            if (tid < s) red[tid] += red[tid + s];
            __syncthreads();
        }
        if (tid == 0) out[gid * 2 + c] = red[0] * inv + outBs[c] * (ssum * inv);
        __syncthreads();
    }
}

static inline size_t alup(size_t x) { return (x + 255) & ~(size_t)255; }

extern "C" void kernel_launch(void* const* d_in, const int* in_sizes, int n_in,
                              void* d_out, int out_size, void* d_ws, size_t ws_size,
                              hipStream_t stream)
{
    const int*   nodes  = (const int*)d_in[0];
    const int*   gsizes = (const int*)d_in[1];
    const int*   edges  = (const int*)d_in[2];
    const float* embed  = (const float*)d_in[3];
    const float* type_w = (const float*)d_in[4];
    const float* type_b = (const float*)d_in[5];
    const float* gru_W  = (const float*)d_in[6];
    const float* gru_U  = (const float*)d_in[7];
    const float* gru_bi = (const float*)d_in[8];
    const float* gru_br = (const float*)d_in[9];
    const float* gate_W = (const float*)d_in[10];
    const float* gate_b = (const float*)d_in[11];
    const float* out_W  = (const float*)d_in[12];
    const float* out_b  = (const float*)d_in[13];
    float* out = (float*)d_out;

    const int CHMAX = 50000;
    const int c0s[2] = {0, 50000};
    const int nrs[2] = {50000, 50000};

    // ---- workspace layout (bytes), total ~241 MB ----
    const size_t SZ_HB   = alup((size_t)N_NODES * H * 2);
    const size_t SZ_SCR1 = alup((size_t)CHMAX * 1024 * 2);
    const size_t SZ_SCR2 = alup((size_t)CHMAX * 256 * 2);
    const size_t SZ_G    = alup((size_t)N_NODES * 4);
    const size_t SZ_PE   = alup((size_t)(L_POS + 1) * H * 4);
    const size_t SZ_WST  = alup((size_t)2 * 256 * 1024 * 2);
    const size_t SZ_BC   = alup((size_t)2 * 1024 * 512 * 2);
    const size_t SZ_BIAS = alup((size_t)2 * 1024 * 4);
    const size_t SZ_CNT4 = alup((size_t)NBUCK4 * 4);
    const size_t SZ_CUR  = alup((size_t)N_NODES * 4);
    const size_t SZ_ACC  = alup((size_t)N_GRAPHS * 256 * 4);
    const size_t SZ_OFF  = alup((size_t)(N_NODES + 1) * 4);
    const size_t SZ_SRC  = alup((size_t)N_EDGES * 4);
    const size_t SZ_PART = alup((size_t)NBLKT * 4);
    const size_t SZ_GMS  = alup((size_t)N_GRAPHS * 4);
    size_t need = 2 * SZ_HB + SZ_SCR1 + SZ_SCR2 + SZ_G + SZ_PE + SZ_WST + SZ_BC + SZ_BIAS +
                  SZ_CNT4 + SZ_CUR + SZ_ACC + SZ_OFF + SZ_SRC + SZ_PART + 2 * SZ_GMS;
    if (ws_size < need) return;

    char* base = (char*)d_ws;
    short* hA     = (short*)base;  base += SZ_HB;
    short* hB     = (short*)base;  base += SZ_HB;
    short* scr1   = (short*)base;  base += SZ_SCR1;
    short* scr2   = (short*)base;  base += SZ_SCR2;
    float* g      = (float*)base;  base += SZ_G;
    float* peTab  = (float*)base;  base += SZ_PE;
    short* Wstack = (short*)base;  base += SZ_WST;
    short* Bcomb  = (short*)base;  base += SZ_BC;
    float* biasC  = (float*)base;  base += SZ_BIAS;
    int*   counts4= (int*)base;    base += SZ_CNT4;
    int*   cursors= (int*)base;    base += SZ_CUR;
    float* accb   = (float*)base;  base += SZ_ACC;
    int*   offs   = (int*)base;    base += SZ_OFF;
    int*   srcs   = (int*)base;    base += SZ_SRC;
    int*   partial= (int*)base;    base += SZ_PART;
    float* gm     = (float*)base;  base += SZ_GMS;
    float* gs     = (float*)base;  base += SZ_GMS;

    // ---- prep ----
    pe_kernel<<<L_POS + 1, 256, 0, stream>>>(peTab);
    cvt_wstack<<<(2 * 256 * 1024) / 256, 256, 0, stream>>>(type_w, Wstack);
    cvt_comb<<<(2 * 1024 * 512) / 256, 256, 0, stream>>>(gru_W, gru_U, Bcomb);
    cvt_bias<<<8, 256, 0, stream>>>(gru_bi, gru_br, biasC);
    {   // zero counts4 + cursors + accb (contiguous)
        int n4 = (int)((SZ_CNT4 + SZ_CUR + SZ_ACC) / 16);
        zero_int<<<(n4 + 255) / 256, 256, 0, stream>>>((int4*)counts4, n4);
    }
    histo_kernel<<<(N_EDGES + 255) / 256, 256, 0, stream>>>(edges, counts4);
    scan1<<<NBLKT, 256, 0, stream>>>(counts4, partial);
    scan2<<<1, 64, 0, stream>>>(partial, offs);
    scan3<<<NBLKT, 256, 0, stream>>>(counts4, partial, offs);
    fill_kernel<<<(N_EDGES + 255) / 256, 256, 0, stream>>>(edges, offs, cursors, srcs);
    init_h_kernel<<<N_NODES, H, 0, stream>>>(nodes, embed, peTab, hA);

    short* cur = hA;
    short* nxt = hB;
    const int steps[2] = {3, 1};
    for (int l = 0; l < 2; l++) {
        const short* WS = Wstack + (size_t)l * 256 * 1024;
        const float* Tb = type_b + (size_t)l * 4 * 256;
        const short* BC = Bcomb + (size_t)l * 1024 * 512;
        const float* Cb = biasC + (size_t)l * 1024;
        for (int s = 0; s < steps[l]; s++) {
            for (int c = 0; c < 2; c++) {
                int c0 = c0s[c], nr = nrs[c];
                int nMb = (nr + 127) / 128;
                int mpx = (nMb + 7) / 8;
                gather_kernel<<<(nr * 64 + 255) / 256, 256, 0, stream>>>(offs, srcs, cur, scr1, c0, nr);
                dim3 g1(8, 2 * mpx);   // nNb=2 (nbShift=1)
                mm_bf16<<<g1, 256, 0, stream>>>(scr1, 1024, nullptr, 0, 1024,
                                                WS, 1024, Tb, counts4, c0,
                                                scr2, 256, nr, 1);
                dim3 g2(8, 8 * mpx);   // nNb=8
                mm_gru<<<g2, 256, 0, stream>>>(scr2, cur + (size_t)c0 * H,
                                               BC, Cb, cur, nxt, c0, nr);
            }
            short* t = cur; cur = nxt; nxt = t;
        }
    }

    gate_kernel<<<(N_NODES * 64) / 256, 256, 0, stream>>>(cur, gate_W, gate_b, g);
    outA_kernel<<<N_GRAPHS, 256, 0, stream>>>(g, gsizes, gm, gs);
    outB_kernel<<<N_GRAPHS * OSLICE, 256, 0, stream>>>(cur, g, gsizes, gm, accb);
    outC_kernel<<<N_GRAPHS, 256, 0, stream>>>(accb, gs, out_W, out_b, out);
}